// Round 8
// baseline (749.661 us; speedup 1.0000x reference)
//
#include <hip/hip_runtime.h>
#include <hip/hip_bf16.h>

// ===================================================================================
// Verified (R6): argmin must bit-replicate numpy-f32:
//   zp  = einsum SSE mod-4 accumulators (l0..l3), reduce (l0+l1)+(l2+l3), + bq
//   A,B = pairwise f32 row-sum-of-squares (AVX512 npyv tree for n=64)
//   d   = fl32( fl32(A + B_k) - fl32(2*M_k) ),  M_k in SSE mod-4 order, first-index ties
// R8: two-phase argmin. Phase-1 FMA scan (fast, approximate to ~1e-8) finds all k with
// m_k <= m_min + DELTA (DELTA = 1.6e-5 > ulp(64)=7.63e-6 + slop; the np subtraction
// quantizes d to the ulp(64) grid, so every np-winner is within that window).
// Phase-2 re-evaluates candidates with np-exact f32 semantics (contract off).
// ===================================================================================

#define KSPLIT 8
#define DELTA 1.6e-5f

__device__ __forceinline__ float np_pairwise64_sq(const float* __restrict__ p) {
    #pragma clang fp contract(off)
    float v[16];
#pragma unroll
    for (int j = 0; j < 16; ++j) {
        float x0 = p[j]      * p[j];
        float x1 = p[j + 32] * p[j + 32];
        float x2 = p[j + 16] * p[j + 16];
        float x3 = p[j + 48] * p[j + 48];
        float r0 = x0 + x1;
        float r1 = x2 + x3;
        v[j] = r0 + r1;
    }
    float s[8], t[4];
#pragma unroll
    for (int j = 0; j < 8; ++j) s[j] = v[j] + v[j + 8];
#pragma unroll
    for (int j = 0; j < 4; ++j) t[j] = s[j] + s[j + 4];
    return (t[0] + t[2]) + (t[1] + t[3]);
}

// ---------------- zp = einsum-SSE f32 dot + bq (np-exact) ----------------
__global__ __launch_bounds__(64) void k_zp_np(const float* __restrict__ z,
                                              const float* __restrict__ Wq,
                                              const float* __restrict__ bq,
                                              float* __restrict__ zp32,
                                              int DIN, int CD) {
    #pragma clang fp contract(off)
    extern __shared__ float zl[];
    const int t = blockIdx.x;
    const int tid = threadIdx.x;
    for (int i = tid; i < DIN; i += 64) zl[i] = z[(size_t)t * DIN + i];
    __syncthreads();
    const int main8 = DIN & ~7;
    for (int c = tid; c < CD; c += 64) {
        const float* wr = Wq + (size_t)c * DIN;
        float l0 = 0.f, l1 = 0.f, l2 = 0.f, l3 = 0.f;
        for (int m = 0; m < main8; m += 4) {
            l0 += zl[m]     * wr[m];
            l1 += zl[m + 1] * wr[m + 1];
            l2 += zl[m + 2] * wr[m + 2];
            l3 += zl[m + 3] * wr[m + 3];
        }
        float acc = (l0 + l1) + (l2 + l3);
        for (int i = main8; i < DIN; ++i) acc += zl[i] * wr[i];
        zp32[(size_t)t * CD + c] = acc + bq[c];
    }
}

// ---------------- A / B: np pairwise sum of squares ----------------
__global__ __launch_bounds__(256) void k_rowsum2_np(const float* __restrict__ src,
                                                    float* __restrict__ dst,
                                                    int rows) {
    #pragma clang fp contract(off)
    const int r = blockIdx.x * 256 + threadIdx.x;
    if (r >= rows) return;
    dst[r] = np_pairwise64_sq(src + (size_t)r * 64);
}

__global__ __launch_bounds__(256) void k_rowsum2_gen(const float* __restrict__ src,
                                                     float* __restrict__ dst,
                                                     int rows, int CD) {
    #pragma clang fp contract(off)
    const int r = blockIdx.x * 256 + threadIdx.x;
    if (r >= rows) return;
    const float* p = src + (size_t)r * CD;
    if (CD < 8) {
        float a = 0.f;
        for (int i = 0; i < CD; ++i) a += p[i] * p[i];
        dst[r] = a;
        return;
    }
    float acc[8];
#pragma unroll
    for (int j = 0; j < 8; ++j) acc[j] = p[j] * p[j];
    const int main8 = CD & ~7;
    for (int i = 8; i < main8; i += 8)
#pragma unroll
        for (int j = 0; j < 8; ++j) acc[j] += p[i + j] * p[i + j];
    float res = ((acc[0] + acc[1]) + (acc[2] + acc[3])) + ((acc[4] + acc[5]) + (acc[6] + acc[7]));
    for (int i = main8; i < CD; ++i) res += p[i] * p[i];
    dst[r] = res;
}

// ---------------- phase-1: FMA scan, per-thread top-3 of m = B - 2*zp.e ----------------
// lane=token (64/block), wave w covers codes [w*32,(w+1)*32) of each 128-tile,
// grid.y = KSPLIT K-slices. e reads are wave-uniform LDS broadcasts (0 conflicts).
__global__ __launch_bounds__(256) void k_scan_f(const float* __restrict__ emb,
                                                const float* __restrict__ zp32,
                                                const float* __restrict__ B32,
                                                float* __restrict__ pm,
                                                int* __restrict__ pj,
                                                int tokens, int K) {
    __shared__ float s_e[128 * 64];
    __shared__ float s_B[128];

    const int tid  = threadIdx.x;
    const int w    = tid >> 6;
    const int lane = tid & 63;
    const int tok  = blockIdx.x * 64 + lane;
    const int trd  = (tok < tokens) ? tok : 0;
    const int kslice = K / KSPLIT;
    const int kbase  = blockIdx.y * kslice;

    float zp[64];
    {
        const float4* zsrc = (const float4*)(zp32 + (size_t)trd * 64);
#pragma unroll
        for (int i = 0; i < 16; ++i) {
            float4 v = zsrc[i];
            zp[4*i] = v.x; zp[4*i+1] = v.y; zp[4*i+2] = v.z; zp[4*i+3] = v.w;
        }
    }

    float m1 = 3.0e38f, m2 = 3.0e38f, m3 = 3.0e38f;
    int   j1 = 0x7fffffff, j2 = 0x7fffffff, j3 = 0x7fffffff;

    for (int t0 = 0; t0 < kslice; t0 += 128) {
        __syncthreads();
        {
            const float4* src = (const float4*)(emb + (size_t)(kbase + t0) * 64);
            float4* dst = (float4*)s_e;
#pragma unroll
            for (int i = 0; i < 8; ++i) dst[tid + i * 256] = src[tid + i * 256];
            if (tid < 128) s_B[tid] = B32[kbase + t0 + tid];
        }
        __syncthreads();

#pragma unroll 2
        for (int kk = 0; kk < 32; kk += 2) {
            const int k0 = w * 32 + kk;
            const int k1 = k0 + 1;
            const float4* e0 = (const float4*)(s_e + k0 * 64);
            const float4* e1 = (const float4*)(s_e + k1 * 64);
            float a0 = 0.f, a1 = 0.f, a2 = 0.f, a3 = 0.f;
            float b0 = 0.f, b1 = 0.f, b2 = 0.f, b3 = 0.f;
#pragma unroll
            for (int c = 0; c < 16; ++c) {
                const float4 x = e0[c];
                const float4 y = e1[c];
                a0 += zp[4*c]   * x.x;  b0 += zp[4*c]   * y.x;   // FMA-contracted
                a1 += zp[4*c+1] * x.y;  b1 += zp[4*c+1] * y.y;
                a2 += zp[4*c+2] * x.z;  b2 += zp[4*c+2] * y.z;
                a3 += zp[4*c+3] * x.w;  b3 += zp[4*c+3] * y.w;
            }
            const float M0 = (a0 + a1) + (a2 + a3);
            const float M1 = (b0 + b1) + (b2 + b3);
            const float d0 = s_B[k0] - 2.f * M0;
            const float d1 = s_B[k1] - 2.f * M1;
            const int kg0 = kbase + t0 + k0;
            if (d0 < m3) {
                if (d0 < m1)      { m3=m2;j3=j2; m2=m1;j2=j1; m1=d0;j1=kg0; }
                else if (d0 < m2) { m3=m2;j3=j2; m2=d0;j2=kg0; }
                else              { m3=d0;j3=kg0; }
            }
            if (d1 < m3) {
                if (d1 < m1)      { m3=m2;j3=j2; m2=m1;j2=j1; m1=d1;j1=kg0+1; }
                else if (d1 < m2) { m3=m2;j3=j2; m2=d1;j2=kg0+1; }
                else              { m3=d1;j3=kg0+1; }
            }
        }
    }

    if (tok < tokens) {
        const size_t slot = (size_t)(blockIdx.y * 4 + w);
        pm[(slot * 3 + 0) * tokens + tok] = m1;  pj[(slot * 3 + 0) * tokens + tok] = j1;
        pm[(slot * 3 + 1) * tokens + tok] = m2;  pj[(slot * 3 + 1) * tokens + tok] = j2;
        pm[(slot * 3 + 2) * tokens + tok] = m3;  pj[(slot * 3 + 2) * tokens + tok] = j3;
    }
}

// ---------------- phase-2: candidate merge + np-exact refine ----------------
__global__ __launch_bounds__(256) void k_refine(const float* __restrict__ emb,
                                                const float* __restrict__ zp32,
                                                const float* __restrict__ A32,
                                                const float* __restrict__ B32,
                                                const float* __restrict__ pm,
                                                const int* __restrict__ pj,
                                                int nslots3, int tokens,
                                                int* __restrict__ idx,
                                                float* __restrict__ out_idx) {
    #pragma clang fp contract(off)
    const int t = blockIdx.x * 256 + threadIdx.x;
    if (t >= tokens) return;

    float mmin = 3.0e38f;
    for (int s = 0; s < nslots3; ++s) {
        const float v = pm[(size_t)s * tokens + t];
        if (v < mmin) mmin = v;
    }
    const float lim = mmin + DELTA;

    int cj[8];
    int nc = 0;
    for (int s = 0; s < nslots3; ++s) {
        const float v = pm[(size_t)s * tokens + t];
        if (v <= lim) {
            const int j = pj[(size_t)s * tokens + t];
            if (nc < 8) {
                int p = nc++;
                while (p > 0 && cj[p-1] > j) { cj[p] = cj[p-1]; --p; }
                cj[p] = j;
            }
        }
    }

    const float A = A32[t];
    const float* zp = zp32 + (size_t)t * 64;
    float best = 3.0e38f;
    int bj = 0x7fffffff;
    for (int c = 0; c < nc; ++c) {
        const int j = cj[c];
        const float* e = emb + (size_t)j * 64;
        float l0 = 0.f, l1 = 0.f, l2 = 0.f, l3 = 0.f;
        for (int m = 0; m < 64; m += 4) {
            l0 += zp[m]     * e[m];
            l1 += zp[m + 1] * e[m + 1];
            l2 += zp[m + 2] * e[m + 2];
            l3 += zp[m + 3] * e[m + 3];
        }
        const float M = (l0 + l1) + (l2 + l3);
        const float S = A + B32[j];
        const float d = S - 2.f * M;
        if (d < best) { best = d; bj = j; }   // ascending j + strict < = first index
    }
    idx[t] = bj;
    out_idx[t] = (float)bj;
}

// ---------------- generic np-exact fallback (any CD%4==0, any K) ----------------
__global__ __launch_bounds__(256) void k_scan_gen(const float* __restrict__ emb,
                                                  const float* __restrict__ zp32,
                                                  const float* __restrict__ A32,
                                                  const float* __restrict__ B32,
                                                  int* __restrict__ idx,
                                                  float* __restrict__ out_idx,
                                                  int K, int CD) {
    #pragma clang fp contract(off)
    extern __shared__ float sm[];
    float* zp = sm;
    float* rm = zp + CD;
    int*   rj = (int*)(rm + 256);
    const int t = blockIdx.x;
    const int tid = threadIdx.x;
    for (int i = tid; i < CD; i += 256) zp[i] = zp32[(size_t)t * CD + i];
    __syncthreads();
    const float A = A32[t];
    float m1 = 3.0e38f; int j1 = 0x7fffffff;
    const int main8 = CD & ~7;
    for (int k = tid; k < K; k += 256) {
        const float* e = emb + (size_t)k * CD;
        float l0 = 0.f, l1 = 0.f, l2 = 0.f, l3 = 0.f;
        for (int m = 0; m < main8; m += 4) {
            l0 += zp[m]     * e[m];
            l1 += zp[m + 1] * e[m + 1];
            l2 += zp[m + 2] * e[m + 2];
            l3 += zp[m + 3] * e[m + 3];
        }
        float M = (l0 + l1) + (l2 + l3);
        for (int i = main8; i < CD; ++i) M += zp[i] * e[i];
        float S = A + B32[k];
        float d = S - 2.f * M;
        if (d < m1) { m1 = d; j1 = k; }
    }
    rm[tid] = m1; rj[tid] = j1;
    __syncthreads();
    if (tid == 0) {
        float gm = 3.0e38f; int gj = 0x7fffffff;
        for (int s = 0; s < 256; ++s) {
            if (rm[s] < gm || (rm[s] == gm && rj[s] < gj)) { gm = rm[s]; gj = rj[s]; }
        }
        idx[t] = gj;
        out_idx[t] = (float)gj;
    }
}

// ---------------- out = (zp + (emb[idx]-zp)) @ Wp^T + bp  (FMA ok) ----------------
__global__ __launch_bounds__(256) void k_out(const float* __restrict__ emb,
                                             const float* __restrict__ zp32,
                                             const int* __restrict__ idx,
                                             const float* __restrict__ Wp,
                                             const float* __restrict__ bp,
                                             float* __restrict__ out,
                                             int DOUT, int CD) {
    extern __shared__ float zq[];
    const int t = blockIdx.x;
    const int tid = threadIdx.x;
    const int k = idx[t];
    for (int i = tid; i < CD; i += 256) {
        const float zpv = zp32[(size_t)t * CD + i];
        zq[i] = zpv + (emb[(size_t)k * CD + i] - zpv);
    }
    __syncthreads();
    for (int d = tid; d < DOUT; d += 256) {
        const float* w = Wp + (size_t)d * CD;
        float acc = 0.f;
        for (int c = 0; c < CD; ++c) acc += zq[c] * w[c];
        out[(size_t)t * DOUT + d] = acc + bp[d];
    }
}

// ---------------- commit loss = 1.25 * mean(fl(e - zp)^2) ----------------
__global__ __launch_bounds__(256) void k_loss1(const float* __restrict__ zp32,
                                               const float* __restrict__ emb,
                                               const int* __restrict__ idx,
                                               double* __restrict__ part,
                                               long long total, int CD) {
    double acc = 0.0;
    const long long stride = (long long)gridDim.x * 256;
    for (long long e = (long long)blockIdx.x * 256 + threadIdx.x; e < total; e += stride) {
        const long long t = e / CD;
        const int c = (int)(e - t * CD);
        const float df = emb[(size_t)idx[t] * CD + c] - zp32[e];
        acc += (double)df * (double)df;
    }
    __shared__ double red[256];
    red[threadIdx.x] = acc;
    __syncthreads();
    for (int s = 128; s > 0; s >>= 1) {
        if (threadIdx.x < s) red[threadIdx.x] += red[threadIdx.x + s];
        __syncthreads();
    }
    if (threadIdx.x == 0) part[blockIdx.x] = red[0];
}

__global__ __launch_bounds__(256) void k_loss2(const double* __restrict__ part,
                                               float* __restrict__ out_loss,
                                               double denom, int n) {
    __shared__ double red[256];
    const int tid = threadIdx.x;
    red[tid] = (tid < n) ? part[tid] : 0.0;
    __syncthreads();
    for (int s = 128; s > 0; s >>= 1) {
        if (tid < s) red[tid] += red[tid + s];
        __syncthreads();
    }
    if (tid == 0)
        *out_loss = (float)(1.25 * red[0] / denom);
}

extern "C" void kernel_launch(void* const* d_in, const int* in_sizes, int n_in,
                              void* d_out, int out_size, void* d_ws, size_t ws_size,
                              hipStream_t stream) {
    const float* z   = (const float*)d_in[0];
    const float* Wq  = (const float*)d_in[1];
    const float* bq  = (const float*)d_in[2];
    const float* emb = (const float*)d_in[3];
    const float* Wp  = (const float*)d_in[4];
    const float* bp  = (const float*)d_in[5];

    const int CD   = in_sizes[2];
    const int DIN  = in_sizes[1] / CD;
    const int DOUT = in_sizes[5];
    const int K    = in_sizes[3] / CD;
    const long long T = (long long)in_sizes[0] / DIN;

    float* out      = (float*)d_out;
    float* out_idx  = out + (size_t)T * DOUT;
    float* out_loss = out_idx + T;

    char* ws = (char*)d_ws;
    size_t off = 0;
    auto carve = [&](size_t bytes) -> char* {
        char* p = ws + off;
        off = (off + bytes + 255) & ~(size_t)255;
        return p;
    };
    float*  zp32 = (float*)carve((size_t)T * CD * 4);
    float*  A32  = (float*)carve((size_t)T * 4);
    float*  B32  = (float*)carve((size_t)K * 4);
    int*    idx  = (int*)carve((size_t)T * 4);
    double* part = (double*)carve(128 * 8);
    float*  pm   = (float*)carve((size_t)T * KSPLIT * 4 * 3 * 4);   // 32 slots x top-3
    int*    pj   = (int*)carve((size_t)T * KSPLIT * 4 * 3 * 4);

    k_zp_np<<<dim3((unsigned)T), dim3(64), (size_t)DIN * 4, stream>>>(z, Wq, bq, zp32, DIN, CD);

    if (CD == 64) {
        k_rowsum2_np<<<dim3((unsigned)((T + 255) / 256)), dim3(256), 0, stream>>>(zp32, A32, (int)T);
        k_rowsum2_np<<<dim3((K + 255) / 256), dim3(256), 0, stream>>>(emb, B32, K);
    } else {
        k_rowsum2_gen<<<dim3((unsigned)((T + 255) / 256)), dim3(256), 0, stream>>>(zp32, A32, (int)T, CD);
        k_rowsum2_gen<<<dim3((K + 255) / 256), dim3(256), 0, stream>>>(emb, B32, K, CD);
    }

    if (CD == 64 && K % (KSPLIT * 128) == 0) {
        dim3 grid((unsigned)((T + 63) / 64), KSPLIT);
        k_scan_f<<<grid, dim3(256), 0, stream>>>(emb, zp32, B32, pm, pj, (int)T, K);
        k_refine<<<dim3((unsigned)((T + 255) / 256)), dim3(256), 0, stream>>>(
            emb, zp32, A32, B32, pm, pj, KSPLIT * 4 * 3, (int)T, idx, out_idx);
    } else {
        const size_t sm = (size_t)CD * 4 + 256 * 4 + 256 * 4;
        k_scan_gen<<<dim3((unsigned)T), dim3(256), sm, stream>>>(
            emb, zp32, A32, B32, idx, out_idx, K, CD);
    }

    k_loss1<<<dim3(128), dim3(256), 0, stream>>>(zp32, emb, idx, part, (long long)T * CD, CD);
    k_loss2<<<dim3(1), dim3(256), 0, stream>>>(part, out_loss, (double)T * CD, 128);
    k_out<<<dim3((unsigned)T), dim3(256), (size_t)CD * 4, stream>>>(emb, zp32, idx, Wp, bp, out, DOUT, CD);
}

// Round 9
// 318.651 us; speedup vs baseline: 2.3526x; 2.3526x over previous
//
#include <hip/hip_runtime.h>
#include <hip/hip_bf16.h>

// ===================================================================================
// Verified (R6/R8, absmax 3.05e-5): argmin must bit-replicate numpy-f32:
//   zp  = einsum SSE mod-4 accumulators, reduce (l0+l1)+(l2+l3), + bq
//   A,B = pairwise f32 row-sum-of-squares (AVX512 npyv tree for n=64)
//   d   = fl32( fl32(A + B_k) - fl32(2*M_k) ), M_k in SSE mod-4 order, first-index ties
// R9: phase-1 via bf16 MFMA (32x32x16), single-product eh*zph + baked -B/2 column.
// Phase-1 error sigma ~1e-6 => DELTA = 2.0e-5 window (np grid 7.8e-6 + 6-sigma slack).
// Phase-2 (np-exact, contract-off) evaluates <=8 candidates, ascending index.
// R8 bug fixed: loss partials (128) now fully reduced (R8 halved the loss).
// ===================================================================================

#define DELTA 2.0e-5f

typedef short short8v __attribute__((ext_vector_type(8)));
typedef float floatx16 __attribute__((ext_vector_type(16)));

__device__ __forceinline__ short f2bf(float x) {           // RTNE f32->bf16
    unsigned u = __builtin_bit_cast(unsigned, x);
    unsigned r = (u + 0x7fffu + ((u >> 16) & 1u)) >> 16;
    return (short)r;
}
__device__ __forceinline__ float bf2f(short b) {
    unsigned u = ((unsigned)(unsigned short)b) << 16;
    return __builtin_bit_cast(float, u);
}

__device__ __forceinline__ float np_pairwise64_sq(const float* __restrict__ p) {
    #pragma clang fp contract(off)
    float v[16];
#pragma unroll
    for (int j = 0; j < 16; ++j) {
        float x0 = p[j]      * p[j];
        float x1 = p[j + 32] * p[j + 32];
        float x2 = p[j + 16] * p[j + 16];
        float x3 = p[j + 48] * p[j + 48];
        float r0 = x0 + x1;
        float r1 = x2 + x3;
        v[j] = r0 + r1;
    }
    float s[8], t[4];
#pragma unroll
    for (int j = 0; j < 8; ++j) s[j] = v[j] + v[j + 8];
#pragma unroll
    for (int j = 0; j < 4; ++j) t[j] = s[j] + s[j + 4];
    return (t[0] + t[2]) + (t[1] + t[3]);
}

// ---------------- zp = einsum-SSE f32 dot + bq (np-exact) ----------------
__global__ __launch_bounds__(64) void k_zp_np(const float* __restrict__ z,
                                              const float* __restrict__ Wq,
                                              const float* __restrict__ bq,
                                              float* __restrict__ zp32,
                                              int DIN, int CD) {
    #pragma clang fp contract(off)
    extern __shared__ float zl[];
    const int t = blockIdx.x;
    const int tid = threadIdx.x;
    for (int i = tid; i < DIN; i += 64) zl[i] = z[(size_t)t * DIN + i];
    __syncthreads();
    const int main8 = DIN & ~7;
    for (int c = tid; c < CD; c += 64) {
        const float* wr = Wq + (size_t)c * DIN;
        float l0 = 0.f, l1 = 0.f, l2 = 0.f, l3 = 0.f;
        for (int m = 0; m < main8; m += 4) {
            l0 += zl[m]     * wr[m];
            l1 += zl[m + 1] * wr[m + 1];
            l2 += zl[m + 2] * wr[m + 2];
            l3 += zl[m + 3] * wr[m + 3];
        }
        float acc = (l0 + l1) + (l2 + l3);
        for (int i = main8; i < DIN; ++i) acc += zl[i] * wr[i];
        zp32[(size_t)t * CD + c] = acc + bq[c];
    }
}

// ---------------- A / B: np pairwise sum of squares ----------------
__global__ __launch_bounds__(256) void k_rowsum2_np(const float* __restrict__ src,
                                                    float* __restrict__ dst,
                                                    int rows) {
    #pragma clang fp contract(off)
    const int r = blockIdx.x * 256 + threadIdx.x;
    if (r >= rows) return;
    dst[r] = np_pairwise64_sq(src + (size_t)r * 64);
}

__global__ __launch_bounds__(256) void k_rowsum2_gen(const float* __restrict__ src,
                                                     float* __restrict__ dst,
                                                     int rows, int CD) {
    #pragma clang fp contract(off)
    const int r = blockIdx.x * 256 + threadIdx.x;
    if (r >= rows) return;
    const float* p = src + (size_t)r * CD;
    if (CD < 8) {
        float a = 0.f;
        for (int i = 0; i < CD; ++i) a += p[i] * p[i];
        dst[r] = a;
        return;
    }
    float acc[8];
#pragma unroll
    for (int j = 0; j < 8; ++j) acc[j] = p[j] * p[j];
    const int main8 = CD & ~7;
    for (int i = 8; i < main8; i += 8)
#pragma unroll
        for (int j = 0; j < 8; ++j) acc[j] += p[i + j] * p[i + j];
    float res = ((acc[0] + acc[1]) + (acc[2] + acc[3])) + ((acc[4] + acc[5]) + (acc[6] + acc[7]));
    for (int i = main8; i < CD; ++i) res += p[i] * p[i];
    dst[r] = res;
}

// ---------------- fragment prep: rows (CD=64) -> bf16 hi fragments ----------------
// Fragment layout for 32x32x16 MFMA operand: group g = (tile*4 + kstep)*64 + lane,
// element j: src[tile*32 + (lane&31)][kstep*16 + (lane>>5)*8 + j].
__global__ __launch_bounds__(256) void k_prep_frag(const float* __restrict__ src,
                                                   short8v* __restrict__ fh,
                                                   int ngroups, int nrows) {
    const int g = blockIdx.x * 256 + threadIdx.x;
    if (g >= ngroups) return;
    const int lane = g & 63;
    const int s = (g >> 6) & 3;
    const int tile = g >> 8;
    const int row = tile * 32 + (lane & 31);
    const int k0 = s * 16 + (lane >> 5) * 8;
    short8v h;
    if (row < nrows) {
        const float* p = src + (size_t)row * 64 + k0;
#pragma unroll
        for (int j = 0; j < 8; ++j) h[j] = f2bf(p[j]);
    } else {
#pragma unroll
        for (int j = 0; j < 8; ++j) h[j] = 0;
    }
    fh[g] = h;
}

// bfrag: A-operand column with -0.5*B32[code] at k=0 (lanes half=0, j=0), else 0.
__global__ __launch_bounds__(256) void k_prep_bfrag(const float* __restrict__ B32,
                                                    short8v* __restrict__ bf,
                                                    int ngroups, int K) {
    const int g = blockIdx.x * 256 + threadIdx.x;
    if (g >= ngroups) return;
    const int lane = g & 63;
    const int ct = g >> 6;
    short8v v;
#pragma unroll
    for (int j = 0; j < 8; ++j) v[j] = 0;
    if (lane < 32) {
        const int code = ct * 32 + lane;
        if (code < K) v[0] = f2bf(-0.5f * B32[code]);
    }
    bf[g] = v;
}

// ---------------- phase-1: MFMA scan, per-lane top-2 MAX of acc = M - B/2 ----------
// block = 256 thr = 4 waves; wave w -> token-tile (blockIdx.x*4+w) = 32 tokens,
// lane&31 = token col, lane>>5 = C-row half. grid.y = 8 K-slices. No LDS.
__global__ __launch_bounds__(256) void k_scan_mfma(const short8v* __restrict__ zpf,
                                                   const short8v* __restrict__ ef,
                                                   const short8v* __restrict__ bfr,
                                                   float* __restrict__ pm,
                                                   int* __restrict__ pj,
                                                   int tokens, int K) {
    const int tid  = threadIdx.x;
    const int w    = tid >> 6;
    const int lane = tid & 63;
    const int half = lane >> 5;
    const int tt   = blockIdx.x * 4 + w;            // token tile
    const int tok  = tt * 32 + (lane & 31);
    const int kslice = K / 8;
    const int ct0  = (blockIdx.y * kslice) >> 5;
    const int ntiles = kslice >> 5;

    short8v zh[4];
#pragma unroll
    for (int s = 0; s < 4; ++s) zh[s] = zpf[(tt * 4 + s) * 64 + lane];

    short8v ones;
#pragma unroll
    for (int j = 0; j < 8; ++j) ones[j] = (short)0x3F80;   // bf16(1.0)

    float m1 = -3.0e38f, m2 = -3.0e38f;
    int   j1 = 0x7fffffff, j2 = 0x7fffffff;

    for (int it = 0; it < ntiles; ++it) {
        const int ct = ct0 + it;
        floatx16 acc;
        // acc = (-B/2) column via MFMA with ones
        {
            floatx16 z0;
#pragma unroll
            for (int i = 0; i < 16; ++i) z0[i] = 0.f;
            acc = __builtin_amdgcn_mfma_f32_32x32x16_bf16(bfr[ct * 64 + lane], ones, z0, 0, 0, 0);
        }
#pragma unroll
        for (int s = 0; s < 4; ++s) {
            const short8v eh = ef[(ct * 4 + s) * 64 + lane];
            acc = __builtin_amdgcn_mfma_f32_32x32x16_bf16(eh, zh[s], acc, 0, 0, 0);
        }
        const int jbase = ct * 32 + 4 * half;
#pragma unroll
        for (int r = 0; r < 16; ++r) {
            const float v = acc[r];
            const int j = jbase + ((r & 3) + 8 * (r >> 2));
            const bool g1 = v > m1;
            const bool g2 = v > m2;
            m2 = g1 ? m1 : (g2 ? v : m2);
            j2 = g1 ? j1 : (g2 ? j : j2);
            m1 = g1 ? v : m1;
            j1 = g1 ? j : j1;
        }
    }

    if (tok < tokens) {
        const int sb = (blockIdx.y * 2 + half) * 2;        // 32 slots/token total
        pm[(size_t)(sb + 0) * tokens + tok] = -2.0f * m1;  // back to B-2M scale
        pj[(size_t)(sb + 0) * tokens + tok] = j1;
        pm[(size_t)(sb + 1) * tokens + tok] = -2.0f * m2;
        pj[(size_t)(sb + 1) * tokens + tok] = j2;
    }
}

// ---------------- phase-2: candidate merge + np-exact refine ----------------
__global__ __launch_bounds__(256) void k_refine(const float* __restrict__ emb,
                                                const float* __restrict__ zp32,
                                                const float* __restrict__ A32,
                                                const float* __restrict__ B32,
                                                const float* __restrict__ pm,
                                                const int* __restrict__ pj,
                                                int nslots, int tokens,
                                                int* __restrict__ idx,
                                                float* __restrict__ out_idx) {
    #pragma clang fp contract(off)
    const int t = blockIdx.x * 256 + threadIdx.x;
    if (t >= tokens) return;

    float mmin = 3.0e38f;
    for (int s = 0; s < nslots; ++s) {
        const float v = pm[(size_t)s * tokens + t];
        if (v < mmin) mmin = v;
    }
    const float lim = mmin + DELTA;

    int cj[8];
    int nc = 0;
    for (int s = 0; s < nslots; ++s) {
        const float v = pm[(size_t)s * tokens + t];
        if (v <= lim) {
            const int j = pj[(size_t)s * tokens + t];
            if (nc < 8) {
                int p = nc++;
                while (p > 0 && cj[p - 1] > j) { cj[p] = cj[p - 1]; --p; }
                cj[p] = j;
            }
        }
    }

    const float A = A32[t];
    const float* zp = zp32 + (size_t)t * 64;
    float best = 3.0e38f;
    int bj = 0x7fffffff;
    for (int c = 0; c < nc; ++c) {
        const int j = cj[c];
        const float* e = emb + (size_t)j * 64;
        float l0 = 0.f, l1 = 0.f, l2 = 0.f, l3 = 0.f;
        for (int m = 0; m < 64; m += 4) {
            l0 += zp[m]     * e[m];
            l1 += zp[m + 1] * e[m + 1];
            l2 += zp[m + 2] * e[m + 2];
            l3 += zp[m + 3] * e[m + 3];
        }
        const float M = (l0 + l1) + (l2 + l3);
        const float S = A + B32[j];
        const float d = S - 2.f * M;
        if (d < best) { best = d; bj = j; }   // ascending j + strict < = first index
    }
    idx[t] = bj;
    out_idx[t] = (float)bj;
}

// ---------------- generic np-exact fallback (any CD%4==0, any K) ----------------
__global__ __launch_bounds__(256) void k_scan_gen(const float* __restrict__ emb,
                                                  const float* __restrict__ zp32,
                                                  const float* __restrict__ A32,
                                                  const float* __restrict__ B32,
                                                  int* __restrict__ idx,
                                                  float* __restrict__ out_idx,
                                                  int K, int CD) {
    #pragma clang fp contract(off)
    extern __shared__ float sm[];
    float* zp = sm;
    float* rm = zp + CD;
    int*   rj = (int*)(rm + 256);
    const int t = blockIdx.x;
    const int tid = threadIdx.x;
    for (int i = tid; i < CD; i += 256) zp[i] = zp32[(size_t)t * CD + i];
    __syncthreads();
    const float A = A32[t];
    float m1 = 3.0e38f; int j1 = 0x7fffffff;
    const int main8 = CD & ~7;
    for (int k = tid; k < K; k += 256) {
        const float* e = emb + (size_t)k * CD;
        float l0 = 0.f, l1 = 0.f, l2 = 0.f, l3 = 0.f;
        for (int m = 0; m < main8; m += 4) {
            l0 += zp[m]     * e[m];
            l1 += zp[m + 1] * e[m + 1];
            l2 += zp[m + 2] * e[m + 2];
            l3 += zp[m + 3] * e[m + 3];
        }
        float M = (l0 + l1) + (l2 + l3);
        for (int i = main8; i < CD; ++i) M += zp[i] * e[i];
        float S = A + B32[k];
        float d = S - 2.f * M;
        if (d < m1) { m1 = d; j1 = k; }
    }
    rm[tid] = m1; rj[tid] = j1;
    __syncthreads();
    if (tid == 0) {
        float gm = 3.0e38f; int gj = 0x7fffffff;
        for (int s = 0; s < 256; ++s) {
            if (rm[s] < gm || (rm[s] == gm && rj[s] < gj)) { gm = rm[s]; gj = rj[s]; }
        }
        idx[t] = gj;
        out_idx[t] = (float)gj;
    }
}

// ---------------- out = (zp + (emb[idx]-zp)) @ Wp^T + bp  (FMA ok) ----------------
__global__ __launch_bounds__(256) void k_out(const float* __restrict__ emb,
                                             const float* __restrict__ zp32,
                                             const int* __restrict__ idx,
                                             const float* __restrict__ Wp,
                                             const float* __restrict__ bp,
                                             float* __restrict__ out,
                                             int DOUT, int CD) {
    extern __shared__ float zq[];
    const int t = blockIdx.x;
    const int tid = threadIdx.x;
    const int k = idx[t];
    for (int i = tid; i < CD; i += 256) {
        const float zpv = zp32[(size_t)t * CD + i];
        zq[i] = zpv + (emb[(size_t)k * CD + i] - zpv);
    }
    __syncthreads();
    for (int d = tid; d < DOUT; d += 256) {
        const float* w = Wp + (size_t)d * CD;
        float acc = 0.f;
        for (int c = 0; c < CD; ++c) acc += zq[c] * w[c];
        out[(size_t)t * DOUT + d] = acc + bp[d];
    }
}

// ---------------- commit loss = 1.25 * mean(fl(e - zp)^2) ----------------
__global__ __launch_bounds__(256) void k_loss1(const float* __restrict__ zp32,
                                               const float* __restrict__ emb,
                                               const int* __restrict__ idx,
                                               double* __restrict__ part,
                                               long long total, int CD) {
    double acc = 0.0;
    const long long stride = (long long)gridDim.x * 256;
    for (long long e = (long long)blockIdx.x * 256 + threadIdx.x; e < total; e += stride) {
        const long long t = e / CD;
        const int c = (int)(e - t * CD);
        const float df = emb[(size_t)idx[t] * CD + c] - zp32[e];
        acc += (double)df * (double)df;
    }
    __shared__ double red[256];
    red[threadIdx.x] = acc;
    __syncthreads();
    for (int s = 128; s > 0; s >>= 1) {
        if (threadIdx.x < s) red[threadIdx.x] += red[threadIdx.x + s];
        __syncthreads();
    }
    if (threadIdx.x == 0) part[blockIdx.x] = red[0];
}

__global__ __launch_bounds__(256) void k_loss2(const double* __restrict__ part,
                                               float* __restrict__ out_loss,
                                               double denom, int n) {
    __shared__ double red[256];
    const int tid = threadIdx.x;
    red[tid] = (tid < n) ? part[tid] : 0.0;
    __syncthreads();
    for (int s = 128; s > 0; s >>= 1) {
        if (tid < s) red[tid] += red[tid + s];
        __syncthreads();
    }
    if (tid == 0)
        *out_loss = (float)(1.25 * red[0] / denom);
}

extern "C" void kernel_launch(void* const* d_in, const int* in_sizes, int n_in,
                              void* d_out, int out_size, void* d_ws, size_t ws_size,
                              hipStream_t stream) {
    const float* z   = (const float*)d_in[0];
    const float* Wq  = (const float*)d_in[1];
    const float* bq  = (const float*)d_in[2];
    const float* emb = (const float*)d_in[3];
    const float* Wp  = (const float*)d_in[4];
    const float* bp  = (const float*)d_in[5];

    const int CD   = in_sizes[2];
    const int DIN  = in_sizes[1] / CD;
    const int DOUT = in_sizes[5];
    const int K    = in_sizes[3] / CD;
    const long long T = (long long)in_sizes[0] / DIN;

    float* out      = (float*)d_out;
    float* out_idx  = out + (size_t)T * DOUT;
    float* out_loss = out_idx + T;

    char* ws = (char*)d_ws;
    size_t off = 0;
    auto carve = [&](size_t bytes) -> char* {
        char* p = ws + off;
        off = (off + bytes + 255) & ~(size_t)255;
        return p;
    };
    float*  zp32 = (float*)carve((size_t)T * CD * 4);
    float*  A32  = (float*)carve((size_t)T * 4);
    float*  B32  = (float*)carve((size_t)K * 4);
    int*    idx  = (int*)carve((size_t)T * 4);
    double* part = (double*)carve(128 * 8);

    bool mfma_ok = (CD == 64) && (K % 256 == 0) && (T % 128 == 0);
    short8v* zpf = nullptr; short8v* ef = nullptr; short8v* bfr = nullptr;
    float* pm = nullptr; int* pj = nullptr;
    int ztiles = 0, ctiles = 0;
    if (mfma_ok) {
        ztiles = (int)(T / 32);
        ctiles = K / 32;
        zpf = (short8v*)carve((size_t)ztiles * 256 * 16);
        ef  = (short8v*)carve((size_t)ctiles * 256 * 16);
        bfr = (short8v*)carve((size_t)ctiles * 64 * 16);
        pm  = (float*)carve((size_t)T * 32 * 4);
        pj  = (int*)carve((size_t)T * 32 * 4);
        if (off > ws_size) mfma_ok = false;   // runtime workspace guard
    }

    k_zp_np<<<dim3((unsigned)T), dim3(64), (size_t)DIN * 4, stream>>>(z, Wq, bq, zp32, DIN, CD);

    if (CD == 64) {
        k_rowsum2_np<<<dim3((unsigned)((T + 255) / 256)), dim3(256), 0, stream>>>(zp32, A32, (int)T);
        k_rowsum2_np<<<dim3((K + 255) / 256), dim3(256), 0, stream>>>(emb, B32, K);
    } else {
        k_rowsum2_gen<<<dim3((unsigned)((T + 255) / 256)), dim3(256), 0, stream>>>(zp32, A32, (int)T, CD);
        k_rowsum2_gen<<<dim3((K + 255) / 256), dim3(256), 0, stream>>>(emb, B32, K, CD);
    }

    if (mfma_ok) {
        const int zg = ztiles * 256, cg = ctiles * 256, bg = ctiles * 64;
        k_prep_frag<<<dim3((zg + 255) / 256), dim3(256), 0, stream>>>(zp32, zpf, zg, (int)T);
        k_prep_frag<<<dim3((cg + 255) / 256), dim3(256), 0, stream>>>(emb, ef, cg, K);
        k_prep_bfrag<<<dim3((bg + 255) / 256), dim3(256), 0, stream>>>(B32, bfr, bg, K);

        dim3 grid((unsigned)(T / 128), 8);
        k_scan_mfma<<<grid, dim3(256), 0, stream>>>(zpf, ef, bfr, pm, pj, (int)T, K);
        k_refine<<<dim3((unsigned)((T + 255) / 256)), dim3(256), 0, stream>>>(
            emb, zp32, A32, B32, pm, pj, 32, (int)T, idx, out_idx);
    } else {
        const size_t sm = (size_t)CD * 4 + 256 * 4 + 256 * 4;
        k_scan_gen<<<dim3((unsigned)T), dim3(256), sm, stream>>>(
            emb, zp32, A32, B32, idx, out_idx, K, CD);
    }

    k_loss1<<<dim3(128), dim3(256), 0, stream>>>(zp32, emb, idx, part, (long long)T * CD, CD);
    k_loss2<<<dim3(1), dim3(256), 0, stream>>>(part, out_loss, (double)T * CD, 128);
    k_out<<<dim3((unsigned)T), dim3(256), (size_t)CD * 4, stream>>>(emb, zp32, idx, Wp, bp, out, DOUT, CD);
}

// Round 10
// 220.204 us; speedup vs baseline: 3.4044x; 1.4471x over previous
//
#include <hip/hip_runtime.h>
#include <hip/hip_bf16.h>

// ===================================================================================
// Verified (R6-R9, absmax 3.05e-5): argmin bit-replicates numpy-f32:
//   zp  = einsum SSE mod-4 accumulators, reduce (l0+l1)+(l2+l3), + bq
//   A,B = pairwise f32 row-sum-of-squares (AVX512 npyv tree for n=64)
//   d   = fl32( fl32(A + B_k) - fl32(2*M_k) ), first-index ties
// Phase-1 = bf16 MFMA 32x32x16 (M - B/2, baked -B/2 via ones-column MFMA), top-2/lane,
// DELTA=2e-5 window; phase-2 np-exact refine (contract off) over <=8 candidates.
// R10: zp_v2 (LDS-staged Wq, 4-token register blocking), KSPLIT 16 (occupancy),
// loss fused into refine, out_v2 (Wp rows in VGPRs).
// ===================================================================================

#define KSPLIT 16
#define DELTA 2.0e-5f

typedef short short8v __attribute__((ext_vector_type(8)));
typedef float floatx16 __attribute__((ext_vector_type(16)));

__device__ __forceinline__ short f2bf(float x) {           // RTNE f32->bf16
    unsigned u = __builtin_bit_cast(unsigned, x);
    unsigned r = (u + 0x7fffu + ((u >> 16) & 1u)) >> 16;
    return (short)r;
}

__device__ __forceinline__ float np_pairwise64_sq(const float* __restrict__ p) {
    #pragma clang fp contract(off)
    float v[16];
#pragma unroll
    for (int j = 0; j < 16; ++j) {
        float x0 = p[j]      * p[j];
        float x1 = p[j + 32] * p[j + 32];
        float x2 = p[j + 16] * p[j + 16];
        float x3 = p[j + 48] * p[j + 48];
        float r0 = x0 + x1;
        float r1 = x2 + x3;
        v[j] = r0 + r1;
    }
    float s[8], t[4];
#pragma unroll
    for (int j = 0; j < 8; ++j) s[j] = v[j] + v[j + 8];
#pragma unroll
    for (int j = 0; j < 4; ++j) t[j] = s[j] + s[j + 4];
    return (t[0] + t[2]) + (t[1] + t[3]);
}

// ---------------- zp v2: CD=64, DIN=256, 32 tokens/block, LDS Wq ----------------
__global__ __launch_bounds__(512) void k_zp_v2(const float* __restrict__ z,
                                               const float* __restrict__ Wq,
                                               const float* __restrict__ bq,
                                               float* __restrict__ zp32) {
    __shared__ float wq[64 * 257];      // stride 257: bank=(c+m)%32, 2-way = free
    __shared__ float zl[32 * 256];
    const int tid  = threadIdx.x;
    const int w    = tid >> 6;          // wave 0..7 -> 4 tokens each
    const int lane = tid & 63;          // c
    const int tbase = blockIdx.x * 32;

    for (int i = tid; i < 64 * 256; i += 512) {
        const int c = i >> 8, m = i & 255;
        wq[c * 257 + m] = Wq[i];
    }
    for (int i = tid; i < 32 * 256; i += 512)
        zl[i] = z[(size_t)tbase * 256 + i];
    __syncthreads();

    const float bqc = bq[lane];
    {
        #pragma clang fp contract(off)
        const float* wr  = wq + lane * 257;
        const float* zt0 = zl + (w * 4 + 0) * 256;
        const float* zt1 = zl + (w * 4 + 1) * 256;
        const float* zt2 = zl + (w * 4 + 2) * 256;
        const float* zt3 = zl + (w * 4 + 3) * 256;
        float l[4][4];
#pragma unroll
        for (int i = 0; i < 4; ++i)
#pragma unroll
            for (int j = 0; j < 4; ++j) l[i][j] = 0.f;
        for (int m = 0; m < 256; m += 4) {
            const float w0 = wr[m], w1 = wr[m + 1], w2 = wr[m + 2], w3 = wr[m + 3];
            const float4 p0 = *(const float4*)(zt0 + m);
            const float4 p1 = *(const float4*)(zt1 + m);
            const float4 p2 = *(const float4*)(zt2 + m);
            const float4 p3 = *(const float4*)(zt3 + m);
            l[0][0] += p0.x * w0; l[0][1] += p0.y * w1; l[0][2] += p0.z * w2; l[0][3] += p0.w * w3;
            l[1][0] += p1.x * w0; l[1][1] += p1.y * w1; l[1][2] += p1.z * w2; l[1][3] += p1.w * w3;
            l[2][0] += p2.x * w0; l[2][1] += p2.y * w1; l[2][2] += p2.z * w2; l[2][3] += p2.w * w3;
            l[3][0] += p3.x * w0; l[3][1] += p3.y * w1; l[3][2] += p3.z * w2; l[3][3] += p3.w * w3;
        }
#pragma unroll
        for (int tk = 0; tk < 4; ++tk) {
            const float acc = (l[tk][0] + l[tk][1]) + (l[tk][2] + l[tk][3]);
            zp32[(size_t)(tbase + w * 4 + tk) * 64 + lane] = acc + bqc;
        }
    }
}

// ---------------- zp fallback (np-exact, any dims) ----------------
__global__ __launch_bounds__(64) void k_zp_np(const float* __restrict__ z,
                                              const float* __restrict__ Wq,
                                              const float* __restrict__ bq,
                                              float* __restrict__ zp32,
                                              int DIN, int CD) {
    #pragma clang fp contract(off)
    extern __shared__ float zl[];
    const int t = blockIdx.x;
    const int tid = threadIdx.x;
    for (int i = tid; i < DIN; i += 64) zl[i] = z[(size_t)t * DIN + i];
    __syncthreads();
    const int main8 = DIN & ~7;
    for (int c = tid; c < CD; c += 64) {
        const float* wr = Wq + (size_t)c * DIN;
        float l0 = 0.f, l1 = 0.f, l2 = 0.f, l3 = 0.f;
        for (int m = 0; m < main8; m += 4) {
            l0 += zl[m]     * wr[m];
            l1 += zl[m + 1] * wr[m + 1];
            l2 += zl[m + 2] * wr[m + 2];
            l3 += zl[m + 3] * wr[m + 3];
        }
        float acc = (l0 + l1) + (l2 + l3);
        for (int i = main8; i < DIN; ++i) acc += zl[i] * wr[i];
        zp32[(size_t)t * CD + c] = acc + bq[c];
    }
}

// ---------------- A / B: np pairwise sum of squares ----------------
__global__ __launch_bounds__(256) void k_rowsum2_np(const float* __restrict__ src,
                                                    float* __restrict__ dst,
                                                    int rows) {
    #pragma clang fp contract(off)
    const int r = blockIdx.x * 256 + threadIdx.x;
    if (r >= rows) return;
    dst[r] = np_pairwise64_sq(src + (size_t)r * 64);
}

__global__ __launch_bounds__(256) void k_rowsum2_gen(const float* __restrict__ src,
                                                     float* __restrict__ dst,
                                                     int rows, int CD) {
    #pragma clang fp contract(off)
    const int r = blockIdx.x * 256 + threadIdx.x;
    if (r >= rows) return;
    const float* p = src + (size_t)r * CD;
    if (CD < 8) {
        float a = 0.f;
        for (int i = 0; i < CD; ++i) a += p[i] * p[i];
        dst[r] = a;
        return;
    }
    float acc[8];
#pragma unroll
    for (int j = 0; j < 8; ++j) acc[j] = p[j] * p[j];
    const int main8 = CD & ~7;
    for (int i = 8; i < main8; i += 8)
#pragma unroll
        for (int j = 0; j < 8; ++j) acc[j] += p[i + j] * p[i + j];
    float res = ((acc[0] + acc[1]) + (acc[2] + acc[3])) + ((acc[4] + acc[5]) + (acc[6] + acc[7]));
    for (int i = main8; i < CD; ++i) res += p[i] * p[i];
    dst[r] = res;
}

// ---------------- fragment prep (rows -> bf16 MFMA A-operand fragments) ----------------
__global__ __launch_bounds__(256) void k_prep_frag(const float* __restrict__ src,
                                                   short8v* __restrict__ fh,
                                                   int ngroups, int nrows) {
    const int g = blockIdx.x * 256 + threadIdx.x;
    if (g >= ngroups) return;
    const int lane = g & 63;
    const int s = (g >> 6) & 3;
    const int tile = g >> 8;
    const int row = tile * 32 + (lane & 31);
    const int k0 = s * 16 + (lane >> 5) * 8;
    short8v h;
    if (row < nrows) {
        const float* p = src + (size_t)row * 64 + k0;
#pragma unroll
        for (int j = 0; j < 8; ++j) h[j] = f2bf(p[j]);
    } else {
#pragma unroll
        for (int j = 0; j < 8; ++j) h[j] = 0;
    }
    fh[g] = h;
}

__global__ __launch_bounds__(256) void k_prep_bfrag(const float* __restrict__ B32,
                                                    short8v* __restrict__ bf,
                                                    int ngroups, int K) {
    const int g = blockIdx.x * 256 + threadIdx.x;
    if (g >= ngroups) return;
    const int lane = g & 63;
    const int ct = g >> 6;
    short8v v;
#pragma unroll
    for (int j = 0; j < 8; ++j) v[j] = 0;
    if (lane < 32) {
        const int code = ct * 32 + lane;
        if (code < K) v[0] = f2bf(-0.5f * B32[code]);
    }
    bf[g] = v;
}

// ---------------- phase-1 MFMA scan: per-lane top-2 MAX of acc = M - B/2 ----------
__global__ __launch_bounds__(256) void k_scan_mfma(const short8v* __restrict__ zpf,
                                                   const short8v* __restrict__ ef,
                                                   const short8v* __restrict__ bfr,
                                                   float* __restrict__ pm,
                                                   int* __restrict__ pj,
                                                   int tokens, int K) {
    const int tid  = threadIdx.x;
    const int w    = tid >> 6;
    const int lane = tid & 63;
    const int half = lane >> 5;
    const int tt   = blockIdx.x * 4 + w;
    const int tok  = tt * 32 + (lane & 31);
    const int kslice = K / KSPLIT;
    const int ct0  = (blockIdx.y * kslice) >> 5;
    const int ntiles = kslice >> 5;

    short8v zh[4];
#pragma unroll
    for (int s = 0; s < 4; ++s) zh[s] = zpf[(tt * 4 + s) * 64 + lane];

    short8v ones;
#pragma unroll
    for (int j = 0; j < 8; ++j) ones[j] = (short)0x3F80;

    float m1 = -3.0e38f, m2 = -3.0e38f;
    int   j1 = 0x7fffffff, j2 = 0x7fffffff;

    for (int it = 0; it < ntiles; ++it) {
        const int ct = ct0 + it;
        floatx16 acc;
        {
            floatx16 z0;
#pragma unroll
            for (int i = 0; i < 16; ++i) z0[i] = 0.f;
            acc = __builtin_amdgcn_mfma_f32_32x32x16_bf16(bfr[ct * 64 + lane], ones, z0, 0, 0, 0);
        }
#pragma unroll
        for (int s = 0; s < 4; ++s) {
            const short8v eh = ef[(ct * 4 + s) * 64 + lane];
            acc = __builtin_amdgcn_mfma_f32_32x32x16_bf16(eh, zh[s], acc, 0, 0, 0);
        }
        const int jbase = ct * 32 + 4 * half;
#pragma unroll
        for (int r = 0; r < 16; ++r) {
            const float v = acc[r];
            const int j = jbase + ((r & 3) + 8 * (r >> 2));
            const bool g1 = v > m1;
            const bool g2 = v > m2;
            m2 = g1 ? m1 : (g2 ? v : m2);
            j2 = g1 ? j1 : (g2 ? j : j2);
            m1 = g1 ? v : m1;
            j1 = g1 ? j : j1;
        }
    }

    if (tok < tokens) {
        const int sb = (blockIdx.y * 2 + half) * 2;        // 64 slots/token total
        pm[(size_t)(sb + 0) * tokens + tok] = -2.0f * m1;
        pj[(size_t)(sb + 0) * tokens + tok] = j1;
        pm[(size_t)(sb + 1) * tokens + tok] = -2.0f * m2;
        pj[(size_t)(sb + 1) * tokens + tok] = j2;
    }
}

// ---------------- phase-2: candidate merge + np-exact refine + fused loss ----------
__global__ __launch_bounds__(256) void k_refine(const float* __restrict__ emb,
                                                const float* __restrict__ zp32,
                                                const float* __restrict__ A32,
                                                const float* __restrict__ B32,
                                                const float* __restrict__ pm,
                                                const int* __restrict__ pj,
                                                int nslots, int tokens,
                                                int* __restrict__ idx,
                                                float* __restrict__ out_idx,
                                                double* __restrict__ ploss) {
    #pragma clang fp contract(off)
    const int t = blockIdx.x * 256 + threadIdx.x;
    if (t >= tokens) return;

    float mmin = 3.0e38f;
    for (int s = 0; s < nslots; ++s) {
        const float v = pm[(size_t)s * tokens + t];
        if (v < mmin) mmin = v;
    }
    const float lim = mmin + DELTA;

    int cj[8];
    int nc = 0;
    for (int s = 0; s < nslots; ++s) {
        const float v = pm[(size_t)s * tokens + t];
        if (v <= lim) {
            const int j = pj[(size_t)s * tokens + t];
            if (nc < 8) {
                int p = nc++;
                while (p > 0 && cj[p - 1] > j) { cj[p] = cj[p - 1]; --p; }
                cj[p] = j;
            }
        }
    }

    const float A = A32[t];
    const float* zp = zp32 + (size_t)t * 64;
    float best = 3.0e38f;
    int bj = 0x7fffffff;
    for (int c = 0; c < nc; ++c) {
        const int j = cj[c];
        const float* e = emb + (size_t)j * 64;
        float l0 = 0.f, l1 = 0.f, l2 = 0.f, l3 = 0.f;
        for (int m = 0; m < 64; m += 4) {
            l0 += zp[m]     * e[m];
            l1 += zp[m + 1] * e[m + 1];
            l2 += zp[m + 2] * e[m + 2];
            l3 += zp[m + 3] * e[m + 3];
        }
        const float M = (l0 + l1) + (l2 + l3);
        const float S = A + B32[j];
        const float d = S - 2.f * M;
        if (d < best) { best = d; bj = j; }
    }
    idx[t] = bj;
    out_idx[t] = (float)bj;

    // fused commit-loss partial: sum over c of fl32(e - zp)^2 (f64 accumulate)
    double ls = 0.0;
    const float* e = emb + (size_t)bj * 64;
    for (int m = 0; m < 64; ++m) {
        const float df = e[m] - zp[m];
        ls += (double)df * (double)df;
    }
    ploss[t] = ls;
}

__global__ __launch_bounds__(256) void k_loss_red(const double* __restrict__ ploss,
                                                  float* __restrict__ out_loss,
                                                  int tokens, double denom) {
    __shared__ double red[256];
    double a = 0.0;
    for (int i = threadIdx.x; i < tokens; i += 256) a += ploss[i];
    red[threadIdx.x] = a;
    __syncthreads();
    for (int s = 128; s > 0; s >>= 1) {
        if (threadIdx.x < s) red[threadIdx.x] += red[threadIdx.x + s];
        __syncthreads();
    }
    if (threadIdx.x == 0) *out_loss = (float)(1.25 * red[0] / denom);
}

// ---------------- generic np-exact fallback scan ----------------
__global__ __launch_bounds__(256) void k_scan_gen(const float* __restrict__ emb,
                                                  const float* __restrict__ zp32,
                                                  const float* __restrict__ A32,
                                                  const float* __restrict__ B32,
                                                  int* __restrict__ idx,
                                                  float* __restrict__ out_idx,
                                                  int K, int CD) {
    #pragma clang fp contract(off)
    extern __shared__ float sm[];
    float* zp = sm;
    float* rm = zp + CD;
    int*   rj = (int*)(rm + 256);
    const int t = blockIdx.x;
    const int tid = threadIdx.x;
    for (int i = tid; i < CD; i += 256) zp[i] = zp32[(size_t)t * CD + i];
    __syncthreads();
    const float A = A32[t];
    float m1 = 3.0e38f; int j1 = 0x7fffffff;
    const int main8 = CD & ~7;
    for (int k = tid; k < K; k += 256) {
        const float* e = emb + (size_t)k * CD;
        float l0 = 0.f, l1 = 0.f, l2 = 0.f, l3 = 0.f;
        for (int m = 0; m < main8; m += 4) {
            l0 += zp[m]     * e[m];
            l1 += zp[m + 1] * e[m + 1];
            l2 += zp[m + 2] * e[m + 2];
            l3 += zp[m + 3] * e[m + 3];
        }
        float M = (l0 + l1) + (l2 + l3);
        for (int i = main8; i < CD; ++i) M += zp[i] * e[i];
        float S = A + B32[k];
        float d = S - 2.f * M;
        if (d < m1) { m1 = d; j1 = k; }
    }
    rm[tid] = m1; rj[tid] = j1;
    __syncthreads();
    if (tid == 0) {
        float gm = 3.0e38f; int gj = 0x7fffffff;
        for (int s = 0; s < 256; ++s) {
            if (rm[s] < gm || (rm[s] == gm && rj[s] < gj)) { gm = rm[s]; gj = rj[s]; }
        }
        idx[t] = gj;
        out_idx[t] = (float)gj;
    }
}

// ---------------- out v2: DOUT=256, CD=64, Wp row in VGPRs, 8 tokens/block ----------
__global__ __launch_bounds__(256) void k_out_v2(const float* __restrict__ emb,
                                                const float* __restrict__ zp32,
                                                const int* __restrict__ idx,
                                                const float* __restrict__ Wp,
                                                const float* __restrict__ bp,
                                                float* __restrict__ out) {
    __shared__ float zq[8 * 64];
    const int tid = threadIdx.x;
    const int tbase = blockIdx.x * 8;
    for (int i = tid; i < 512; i += 256) {
        const int tk = i >> 6, c = i & 63;
        const int t = tbase + tk;
        const float zpv = zp32[(size_t)t * 64 + c];
        zq[i] = zpv + (emb[(size_t)idx[t] * 64 + c] - zpv);
    }
    float4 wp[16];
#pragma unroll
    for (int i = 0; i < 16; ++i) wp[i] = *(const float4*)(Wp + (size_t)tid * 64 + i * 4);
    const float bpd = bp[tid];
    __syncthreads();
#pragma unroll
    for (int tk = 0; tk < 8; ++tk) {
        const float* zr = zq + tk * 64;
        float acc = 0.f;
#pragma unroll
        for (int i = 0; i < 16; ++i) {
            const float4 p = *(const float4*)(zr + i * 4);
            acc += p.x * wp[i].x + p.y * wp[i].y + p.z * wp[i].z + p.w * wp[i].w;
        }
        out[(size_t)(tbase + tk) * 256 + tid] = acc + bpd;
    }
}

// ---------------- out fallback ----------------
__global__ __launch_bounds__(256) void k_out(const float* __restrict__ emb,
                                             const float* __restrict__ zp32,
                                             const int* __restrict__ idx,
                                             const float* __restrict__ Wp,
                                             const float* __restrict__ bp,
                                             float* __restrict__ out,
                                             int DOUT, int CD) {
    extern __shared__ float zq[];
    const int t = blockIdx.x;
    const int tid = threadIdx.x;
    const int k = idx[t];
    for (int i = tid; i < CD; i += 256) {
        const float zpv = zp32[(size_t)t * CD + i];
        zq[i] = zpv + (emb[(size_t)k * CD + i] - zpv);
    }
    __syncthreads();
    for (int d = tid; d < DOUT; d += 256) {
        const float* w = Wp + (size_t)d * CD;
        float acc = 0.f;
        for (int c = 0; c < CD; ++c) acc += zq[c] * w[c];
        out[(size_t)t * DOUT + d] = acc + bp[d];
    }
}

// ---------------- loss fallback ----------------
__global__ __launch_bounds__(256) void k_loss1(const float* __restrict__ zp32,
                                               const float* __restrict__ emb,
                                               const int* __restrict__ idx,
                                               double* __restrict__ part,
                                               long long total, int CD) {
    double acc = 0.0;
    const long long stride = (long long)gridDim.x * 256;
    for (long long e = (long long)blockIdx.x * 256 + threadIdx.x; e < total; e += stride) {
        const long long t = e / CD;
        const int c = (int)(e - t * CD);
        const float df = emb[(size_t)idx[t] * CD + c] - zp32[e];
        acc += (double)df * (double)df;
    }
    __shared__ double red[256];
    red[threadIdx.x] = acc;
    __syncthreads();
    for (int s = 128; s > 0; s >>= 1) {
        if (threadIdx.x < s) red[threadIdx.x] += red[threadIdx.x + s];
        __syncthreads();
    }
    if (threadIdx.x == 0) part[blockIdx.x] = red[0];
}

__global__ __launch_bounds__(256) void k_loss2(const double* __restrict__ part,
                                               float* __restrict__ out_loss,
                                               double denom, int n) {
    __shared__ double red[256];
    const int tid = threadIdx.x;
    red[tid] = (tid < n) ? part[tid] : 0.0;
    __syncthreads();
    for (int s = 128; s > 0; s >>= 1) {
        if (tid < s) red[tid] += red[tid + s];
        __syncthreads();
    }
    if (tid == 0) *out_loss = (float)(1.25 * red[0] / denom);
}

extern "C" void kernel_launch(void* const* d_in, const int* in_sizes, int n_in,
                              void* d_out, int out_size, void* d_ws, size_t ws_size,
                              hipStream_t stream) {
    const float* z   = (const float*)d_in[0];
    const float* Wq  = (const float*)d_in[1];
    const float* bq  = (const float*)d_in[2];
    const float* emb = (const float*)d_in[3];
    const float* Wp  = (const float*)d_in[4];
    const float* bp  = (const float*)d_in[5];

    const int CD   = in_sizes[2];
    const int DIN  = in_sizes[1] / CD;
    const int DOUT = in_sizes[5];
    const int K    = in_sizes[3] / CD;
    const long long T = (long long)in_sizes[0] / DIN;

    float* out      = (float*)d_out;
    float* out_idx  = out + (size_t)T * DOUT;
    float* out_loss = out_idx + T;

    char* ws = (char*)d_ws;
    size_t off = 0;
    auto carve = [&](size_t bytes) -> char* {
        char* p = ws + off;
        off = (off + bytes + 255) & ~(size_t)255;
        return p;
    };
    float*  zp32  = (float*)carve((size_t)T * CD * 4);
    float*  A32   = (float*)carve((size_t)T * 4);
    float*  B32   = (float*)carve((size_t)K * 4);
    int*    idx   = (int*)carve((size_t)T * 4);
    double* part  = (double*)carve(128 * 8);
    double* ploss = (double*)carve((size_t)T * 8);

    bool mfma_ok = (CD == 64) && (K % (KSPLIT * 32) == 0) && (T % 128 == 0);
    short8v* zpf = nullptr; short8v* ef = nullptr; short8v* bfr = nullptr;
    float* pm = nullptr; int* pj = nullptr;
    int ztiles = 0, ctiles = 0;
    if (mfma_ok) {
        ztiles = (int)(T / 32);
        ctiles = K / 32;
        zpf = (short8v*)carve((size_t)ztiles * 256 * 16);
        ef  = (short8v*)carve((size_t)ctiles * 256 * 16);
        bfr = (short8v*)carve((size_t)ctiles * 64 * 16);
        pm  = (float*)carve((size_t)T * KSPLIT * 4 * 4);
        pj  = (int*)carve((size_t)T * KSPLIT * 4 * 4);
        if (off > ws_size) mfma_ok = false;
    }

    if (CD == 64 && DIN == 256 && T % 32 == 0) {
        k_zp_v2<<<dim3((unsigned)(T / 32)), dim3(512), 0, stream>>>(z, Wq, bq, zp32);
    } else {
        k_zp_np<<<dim3((unsigned)T), dim3(64), (size_t)DIN * 4, stream>>>(z, Wq, bq, zp32, DIN, CD);
    }

    if (CD == 64) {
        k_rowsum2_np<<<dim3((unsigned)((T + 255) / 256)), dim3(256), 0, stream>>>(zp32, A32, (int)T);
        k_rowsum2_np<<<dim3((K + 255) / 256), dim3(256), 0, stream>>>(emb, B32, K);
    } else {
        k_rowsum2_gen<<<dim3((unsigned)((T + 255) / 256)), dim3(256), 0, stream>>>(zp32, A32, (int)T, CD);
        k_rowsum2_gen<<<dim3((K + 255) / 256), dim3(256), 0, stream>>>(emb, B32, K, CD);
    }

    if (mfma_ok) {
        const int zg = ztiles * 256, cg = ctiles * 256, bg = ctiles * 64;
        k_prep_frag<<<dim3((zg + 255) / 256), dim3(256), 0, stream>>>(zp32, zpf, zg, (int)T);
        k_prep_frag<<<dim3((cg + 255) / 256), dim3(256), 0, stream>>>(emb, ef, cg, K);
        k_prep_bfrag<<<dim3((bg + 255) / 256), dim3(256), 0, stream>>>(B32, bfr, bg, K);

        dim3 grid((unsigned)(T / 128), KSPLIT);
        k_scan_mfma<<<grid, dim3(256), 0, stream>>>(zpf, ef, bfr, pm, pj, (int)T, K);
        k_refine<<<dim3((unsigned)((T + 255) / 256)), dim3(256), 0, stream>>>(
            emb, zp32, A32, B32, pm, pj, KSPLIT * 4, (int)T, idx, out_idx, ploss);
        k_loss_red<<<dim3(1), dim3(256), 0, stream>>>(ploss, out_loss, (int)T, (double)T * CD);
    } else {
        const size_t sm = (size_t)CD * 4 + 256 * 4 + 256 * 4;
        k_scan_gen<<<dim3((unsigned)T), dim3(256), sm, stream>>>(
            emb, zp32, A32, B32, idx, out_idx, K, CD);
        k_loss1<<<dim3(128), dim3(256), 0, stream>>>(zp32, emb, idx, part, (long long)T * CD, CD);
        k_loss2<<<dim3(1), dim3(256), 0, stream>>>(part, out_loss, (double)T * CD, 128);
    }

    if (DOUT == 256 && CD == 64 && T % 8 == 0) {
        k_out_v2<<<dim3((unsigned)(T / 8)), dim3(256), 0, stream>>>(emb, zp32, idx, Wp, bp, out);
    } else {
        k_out<<<dim3((unsigned)T), dim3(256), (size_t)CD * 4, stream>>>(emb, zp32, idx, Wp, bp, out, DOUT, CD);
    }
}

// Round 11
// 211.977 us; speedup vs baseline: 3.5365x; 1.0388x over previous
//
#include <hip/hip_runtime.h>
#include <hip/hip_bf16.h>

// ===================================================================================
// Verified (R6-R10, absmax 3.05e-5): argmin bit-replicates numpy-f32:
//   zp  = einsum SSE mod-4 accumulators, reduce (l0+l1)+(l2+l3), + bq
//   A,B = pairwise f32 row-sum-of-squares (AVX512 npyv tree for n=64)
//   d   = fl32( fl32(A + B_k) - fl32(2*M_k) ), first-index ties
// R11: scan -> two MFMA passes. Pass-1: per-token max of v=M-B/2 (max3 tree, no
// indices). Threshold thv = vmax - 1e-5 (v-units == 2e-5 d-window, same margin as
// R9/R10). Pass-2: bit-identical MFMA re-run, collect all codes with v >= thv via
// rare atomics (candidate set provably contains the np-winner: identical op order
// => identical acc => max re-qualifies). Phase-2 np-exact refine (contract off)
// over <=16 sorted candidates. zp_v3: 2-half LDS staging -> 3 blocks/CU.
// ===================================================================================

#define VWIN 1.0e-5f

typedef short short8v __attribute__((ext_vector_type(8)));
typedef float floatx16 __attribute__((ext_vector_type(16)));

__device__ __forceinline__ short f2bf(float x) {           // RTNE f32->bf16
    unsigned u = __builtin_bit_cast(unsigned, x);
    unsigned r = (u + 0x7fffu + ((u >> 16) & 1u)) >> 16;
    return (short)r;
}

__device__ __forceinline__ float np_pairwise64_sq(const float* __restrict__ p) {
    #pragma clang fp contract(off)
    float v[16];
#pragma unroll
    for (int j = 0; j < 16; ++j) {
        float x0 = p[j]      * p[j];
        float x1 = p[j + 32] * p[j + 32];
        float x2 = p[j + 16] * p[j + 16];
        float x3 = p[j + 48] * p[j + 48];
        float r0 = x0 + x1;
        float r1 = x2 + x3;
        v[j] = r0 + r1;
    }
    float s[8], t[4];
#pragma unroll
    for (int j = 0; j < 8; ++j) s[j] = v[j] + v[j + 8];
#pragma unroll
    for (int j = 0; j < 4; ++j) t[j] = s[j] + s[j + 4];
    return (t[0] + t[2]) + (t[1] + t[3]);
}

// ---------------- zp v3: CD=64, DIN=256, 32 tokens/block, 2-half LDS ----------------
__global__ __launch_bounds__(512) void k_zp_v3(const float* __restrict__ z,
                                               const float* __restrict__ Wq,
                                               const float* __restrict__ bq,
                                               float* __restrict__ zp32) {
    __shared__ float wq[64 * 129];      // stride 129 -> banks (lane+m)%32, 2-way free
    __shared__ float zl[32 * 128];
    const int tid  = threadIdx.x;
    const int w    = tid >> 6;          // wave 0..7 -> 4 tokens each
    const int lane = tid & 63;          // c
    const int tbase = blockIdx.x * 32;

    float l[4][4];
#pragma unroll
    for (int i = 0; i < 4; ++i)
#pragma unroll
        for (int j = 0; j < 4; ++j) l[i][j] = 0.f;

    for (int h = 0; h < 2; ++h) {
        __syncthreads();
        for (int i = tid; i < 64 * 128; i += 512) {
            const int c = i >> 7, m = i & 127;
            wq[c * 129 + m] = Wq[(size_t)c * 256 + h * 128 + m];
        }
        for (int i = tid; i < 32 * 128; i += 512) {
            const int t = i >> 7, m = i & 127;
            zl[t * 128 + m] = z[(size_t)(tbase + t) * 256 + h * 128 + m];
        }
        __syncthreads();
        {
            #pragma clang fp contract(off)
            const float* wr  = wq + lane * 129;
            const float* zt0 = zl + (w * 4 + 0) * 128;
            const float* zt1 = zl + (w * 4 + 1) * 128;
            const float* zt2 = zl + (w * 4 + 2) * 128;
            const float* zt3 = zl + (w * 4 + 3) * 128;
            for (int m = 0; m < 128; m += 4) {
                const float w0 = wr[m], w1 = wr[m + 1], w2 = wr[m + 2], w3 = wr[m + 3];
                const float4 p0 = *(const float4*)(zt0 + m);
                const float4 p1 = *(const float4*)(zt1 + m);
                const float4 p2 = *(const float4*)(zt2 + m);
                const float4 p3 = *(const float4*)(zt3 + m);
                l[0][0] += p0.x * w0; l[0][1] += p0.y * w1; l[0][2] += p0.z * w2; l[0][3] += p0.w * w3;
                l[1][0] += p1.x * w0; l[1][1] += p1.y * w1; l[1][2] += p1.z * w2; l[1][3] += p1.w * w3;
                l[2][0] += p2.x * w0; l[2][1] += p2.y * w1; l[2][2] += p2.z * w2; l[2][3] += p2.w * w3;
                l[3][0] += p3.x * w0; l[3][1] += p3.y * w1; l[3][2] += p3.z * w2; l[3][3] += p3.w * w3;
            }
        }
    }
    {
        #pragma clang fp contract(off)
        const float bqc = bq[lane];
#pragma unroll
        for (int tk = 0; tk < 4; ++tk) {
            const float acc = (l[tk][0] + l[tk][1]) + (l[tk][2] + l[tk][3]);
            zp32[(size_t)(tbase + w * 4 + tk) * 64 + lane] = acc + bqc;
        }
    }
}

// ---------------- zp fallback (np-exact, any dims) ----------------
__global__ __launch_bounds__(64) void k_zp_np(const float* __restrict__ z,
                                              const float* __restrict__ Wq,
                                              const float* __restrict__ bq,
                                              float* __restrict__ zp32,
                                              int DIN, int CD) {
    #pragma clang fp contract(off)
    extern __shared__ float zl[];
    const int t = blockIdx.x;
    const int tid = threadIdx.x;
    for (int i = tid; i < DIN; i += 64) zl[i] = z[(size_t)t * DIN + i];
    __syncthreads();
    const int main8 = DIN & ~7;
    for (int c = tid; c < CD; c += 64) {
        const float* wr = Wq + (size_t)c * DIN;
        float l0 = 0.f, l1 = 0.f, l2 = 0.f, l3 = 0.f;
        for (int m = 0; m < main8; m += 4) {
            l0 += zl[m]     * wr[m];
            l1 += zl[m + 1] * wr[m + 1];
            l2 += zl[m + 2] * wr[m + 2];
            l3 += zl[m + 3] * wr[m + 3];
        }
        float acc = (l0 + l1) + (l2 + l3);
        for (int i = main8; i < DIN; ++i) acc += zl[i] * wr[i];
        zp32[(size_t)t * CD + c] = acc + bq[c];
    }
}

// ---------------- A / B: np pairwise sum of squares ----------------
__global__ __launch_bounds__(256) void k_rowsum2_np(const float* __restrict__ src,
                                                    float* __restrict__ dst,
                                                    int rows) {
    #pragma clang fp contract(off)
    const int r = blockIdx.x * 256 + threadIdx.x;
    if (r >= rows) return;
    dst[r] = np_pairwise64_sq(src + (size_t)r * 64);
}

__global__ __launch_bounds__(256) void k_rowsum2_gen(const float* __restrict__ src,
                                                     float* __restrict__ dst,
                                                     int rows, int CD) {
    #pragma clang fp contract(off)
    const int r = blockIdx.x * 256 + threadIdx.x;
    if (r >= rows) return;
    const float* p = src + (size_t)r * CD;
    if (CD < 8) {
        float a = 0.f;
        for (int i = 0; i < CD; ++i) a += p[i] * p[i];
        dst[r] = a;
        return;
    }
    float acc[8];
#pragma unroll
    for (int j = 0; j < 8; ++j) acc[j] = p[j] * p[j];
    const int main8 = CD & ~7;
    for (int i = 8; i < main8; i += 8)
#pragma unroll
        for (int j = 0; j < 8; ++j) acc[j] += p[i + j] * p[i + j];
    float res = ((acc[0] + acc[1]) + (acc[2] + acc[3])) + ((acc[4] + acc[5]) + (acc[6] + acc[7]));
    for (int i = main8; i < CD; ++i) res += p[i] * p[i];
    dst[r] = res;
}

// ---------------- fragment prep (rows -> bf16 MFMA A-operand fragments) ----------------
__global__ __launch_bounds__(256) void k_prep_frag(const float* __restrict__ src,
                                                   short8v* __restrict__ fh,
                                                   int ngroups, int nrows) {
    const int g = blockIdx.x * 256 + threadIdx.x;
    if (g >= ngroups) return;
    const int lane = g & 63;
    const int s = (g >> 6) & 3;
    const int tile = g >> 8;
    const int row = tile * 32 + (lane & 31);
    const int k0 = s * 16 + (lane >> 5) * 8;
    short8v h;
    if (row < nrows) {
        const float* p = src + (size_t)row * 64 + k0;
#pragma unroll
        for (int j = 0; j < 8; ++j) h[j] = f2bf(p[j]);
    } else {
#pragma unroll
        for (int j = 0; j < 8; ++j) h[j] = 0;
    }
    fh[g] = h;
}

__global__ __launch_bounds__(256) void k_prep_bfrag(const float* __restrict__ B32,
                                                    short8v* __restrict__ bf,
                                                    int ngroups, int K) {
    const int g = blockIdx.x * 256 + threadIdx.x;
    if (g >= ngroups) return;
    const int lane = g & 63;
    const int ct = g >> 6;
    short8v v;
#pragma unroll
    for (int j = 0; j < 8; ++j) v[j] = 0;
    if (lane < 32) {
        const int code = ct * 32 + lane;
        if (code < K) v[0] = f2bf(-0.5f * B32[code]);
    }
    bf[g] = v;
}

// ---------------- pass-1: per-token MAX of v = M - B/2 (no indices) ----------------
// grid (T/512, 32), 256 thr = 4 waves; wave handles 4 token-tiles, e-frags reused x4.
__global__ __launch_bounds__(256) void k_scan_max(const short8v* __restrict__ zpf,
                                                  const short8v* __restrict__ ef,
                                                  const short8v* __restrict__ bfr,
                                                  float* __restrict__ pmax,
                                                  int tokens, int K) {
    const int tid  = threadIdx.x;
    const int w    = tid >> 6;
    const int lane = tid & 63;
    const int half = lane >> 5;
    const int col  = lane & 31;
    const int ttb  = (blockIdx.x * 4 + w) * 4;        // 4 token-tiles per wave
    const int etiles = K / 1024;                      // e-tiles per slice (32 slices)
    const int ct0 = blockIdx.y * etiles;

    short8v zh[4][4];
#pragma unroll
    for (int q = 0; q < 4; ++q)
#pragma unroll
        for (int s = 0; s < 4; ++s) zh[q][s] = zpf[((ttb + q) * 4 + s) * 64 + lane];

    short8v ones;
#pragma unroll
    for (int j = 0; j < 8; ++j) ones[j] = (short)0x3F80;

    float m[4] = {-3.0e38f, -3.0e38f, -3.0e38f, -3.0e38f};

    for (int it = 0; it < etiles; ++it) {
        const int ct = ct0 + it;
        const short8v bfrag = bfr[ct * 64 + lane];
        short8v eh[4];
#pragma unroll
        for (int s = 0; s < 4; ++s) eh[s] = ef[(ct * 4 + s) * 64 + lane];
#pragma unroll
        for (int q = 0; q < 4; ++q) {
            floatx16 acc;
            {
                floatx16 z0;
#pragma unroll
                for (int i = 0; i < 16; ++i) z0[i] = 0.f;
                acc = __builtin_amdgcn_mfma_f32_32x32x16_bf16(bfrag, ones, z0, 0, 0, 0);
            }
#pragma unroll
            for (int s = 0; s < 4; ++s)
                acc = __builtin_amdgcn_mfma_f32_32x32x16_bf16(eh[s], zh[q][s], acc, 0, 0, 0);
            float t0 = fmaxf(acc[0], acc[1]),  t1 = fmaxf(acc[2], acc[3]);
            float t2 = fmaxf(acc[4], acc[5]),  t3 = fmaxf(acc[6], acc[7]);
            float t4 = fmaxf(acc[8], acc[9]),  t5 = fmaxf(acc[10], acc[11]);
            float t6 = fmaxf(acc[12], acc[13]), t7 = fmaxf(acc[14], acc[15]);
            t0 = fmaxf(t0, t1); t2 = fmaxf(t2, t3); t4 = fmaxf(t4, t5); t6 = fmaxf(t6, t7);
            m[q] = fmaxf(m[q], fmaxf(fmaxf(t0, t2), fmaxf(t4, t6)));
        }
    }

#pragma unroll
    for (int q = 0; q < 4; ++q) {
        const int tok = (ttb + q) * 32 + col;
        if (tok < tokens)
            pmax[(size_t)(blockIdx.y * 2 + half) * tokens + tok] = m[q];
    }
}

// ---------------- threshold reduce + counter zero ----------------
__global__ __launch_bounds__(256) void k_thresh(const float* __restrict__ pmax,
                                                float* __restrict__ thv,
                                                int* __restrict__ cnt,
                                                int tokens) {
    const int t = blockIdx.x * 256 + threadIdx.x;
    if (t >= tokens) return;
    float m = -3.0e38f;
    for (int s = 0; s < 64; ++s) m = fmaxf(m, pmax[(size_t)s * tokens + t]);
    thv[t] = m - VWIN;
    cnt[t] = 0;
}

// ---------------- pass-2: collect all codes with v >= thv (bit-identical MFMA) ------
__global__ __launch_bounds__(256) void k_scan_collect(const short8v* __restrict__ zpf,
                                                      const short8v* __restrict__ ef,
                                                      const short8v* __restrict__ bfr,
                                                      const float* __restrict__ thv,
                                                      int* __restrict__ cnt,
                                                      int* __restrict__ cand,
                                                      int tokens, int K) {
    const int tid  = threadIdx.x;
    const int w    = tid >> 6;
    const int lane = tid & 63;
    const int half = lane >> 5;
    const int col  = lane & 31;
    const int ttb  = (blockIdx.x * 4 + w) * 4;
    const int etiles = K / 1024;
    const int ct0 = blockIdx.y * etiles;

    short8v zh[4][4];
#pragma unroll
    for (int q = 0; q < 4; ++q)
#pragma unroll
        for (int s = 0; s < 4; ++s) zh[q][s] = zpf[((ttb + q) * 4 + s) * 64 + lane];

    float tv[4];
    int tokq[4];
#pragma unroll
    for (int q = 0; q < 4; ++q) {
        tokq[q] = (ttb + q) * 32 + col;
        tv[q] = (tokq[q] < tokens) ? thv[tokq[q]] : 3.0e38f;
    }

    short8v ones;
#pragma unroll
    for (int j = 0; j < 8; ++j) ones[j] = (short)0x3F80;

    for (int it = 0; it < etiles; ++it) {
        const int ct = ct0 + it;
        const short8v bfrag = bfr[ct * 64 + lane];
        short8v eh[4];
#pragma unroll
        for (int s = 0; s < 4; ++s) eh[s] = ef[(ct * 4 + s) * 64 + lane];
#pragma unroll
        for (int q = 0; q < 4; ++q) {
            floatx16 acc;
            {
                floatx16 z0;
#pragma unroll
                for (int i = 0; i < 16; ++i) z0[i] = 0.f;
                acc = __builtin_amdgcn_mfma_f32_32x32x16_bf16(bfrag, ones, z0, 0, 0, 0);
            }
#pragma unroll
            for (int s = 0; s < 4; ++s)
                acc = __builtin_amdgcn_mfma_f32_32x32x16_bf16(eh[s], zh[q][s], acc, 0, 0, 0);
            float t0 = fmaxf(acc[0], acc[1]),  t1 = fmaxf(acc[2], acc[3]);
            float t2 = fmaxf(acc[4], acc[5]),  t3 = fmaxf(acc[6], acc[7]);
            float t4 = fmaxf(acc[8], acc[9]),  t5 = fmaxf(acc[10], acc[11]);
            float t6 = fmaxf(acc[12], acc[13]), t7 = fmaxf(acc[14], acc[15]);
            t0 = fmaxf(t0, t1); t2 = fmaxf(t2, t3); t4 = fmaxf(t4, t5); t6 = fmaxf(t6, t7);
            const float tm = fmaxf(fmaxf(t0, t2), fmaxf(t4, t6));
            if (__any(tm >= tv[q])) {          // rare (~10% of tiles)
#pragma unroll
                for (int r = 0; r < 16; ++r) {
                    if (acc[r] >= tv[q]) {
                        const int code = ct * 32 + ((r & 3) + 8 * (r >> 2) + 4 * half);
                        const int p = atomicAdd(&cnt[tokq[q]], 1);
                        if (p < 16) cand[(size_t)tokq[q] * 16 + p] = code;
                    }
                }
            }
        }
    }
}

// ---------------- phase-2: np-exact refine over sorted candidates + fused loss ------
__global__ __launch_bounds__(256) void k_refine_v2(const float* __restrict__ emb,
                                                   const float* __restrict__ zp32,
                                                   const float* __restrict__ A32,
                                                   const float* __restrict__ B32,
                                                   const int* __restrict__ cnt,
                                                   const int* __restrict__ cand,
                                                   int tokens,
                                                   int* __restrict__ idx,
                                                   float* __restrict__ out_idx,
                                                   double* __restrict__ ploss) {
    #pragma clang fp contract(off)
    const int t = blockIdx.x * 256 + threadIdx.x;
    if (t >= tokens) return;

    int n = cnt[t];
    if (n > 16) n = 16;
    int cj[16];
    for (int i = 0; i < n; ++i) {
        const int j = cand[(size_t)t * 16 + i];
        int p = i;
        while (p > 0 && cj[p - 1] > j) { cj[p] = cj[p - 1]; --p; }
        cj[p] = j;
    }

    const float A = A32[t];
    const float* zp = zp32 + (size_t)t * 64;
    float best = 3.0e38f;
    int bj = 0x7fffffff;
    for (int c = 0; c < n; ++c) {
        const int j = cj[c];
        const float* e = emb + (size_t)j * 64;
        float l0 = 0.f, l1 = 0.f, l2 = 0.f, l3 = 0.f;
        for (int m = 0; m < 64; m += 4) {
            l0 += zp[m]     * e[m];
            l1 += zp[m + 1] * e[m + 1];
            l2 += zp[m + 2] * e[m + 2];
            l3 += zp[m + 3] * e[m + 3];
        }
        const float M = (l0 + l1) + (l2 + l3);
        const float S = A + B32[j];
        const float d = S - 2.f * M;
        if (d < best) { best = d; bj = j; }   // ascending j + strict < = first index
    }
    idx[t] = bj;
    out_idx[t] = (float)bj;

    double ls = 0.0;
    const float* e = emb + (size_t)bj * 64;
    for (int m = 0; m < 64; ++m) {
        const float df = e[m] - zp[m];
        ls += (double)df * (double)df;
    }
    ploss[t] = ls;
}

__global__ __launch_bounds__(256) void k_loss_red(const double* __restrict__ ploss,
                                                  float* __restrict__ out_loss,
                                                  int tokens, double denom) {
    __shared__ double red[256];
    double a = 0.0;
    for (int i = threadIdx.x; i < tokens; i += 256) a += ploss[i];
    red[threadIdx.x] = a;
    __syncthreads();
    for (int s = 128; s > 0; s >>= 1) {
        if (threadIdx.x < s) red[threadIdx.x] += red[threadIdx.x + s];
        __syncthreads();
    }
    if (threadIdx.x == 0) *out_loss = (float)(1.25 * red[0] / denom);
}

// ---------------- generic np-exact fallback scan ----------------
__global__ __launch_bounds__(256) void k_scan_gen(const float* __restrict__ emb,
                                                  const float* __restrict__ zp32,
                                                  const float* __restrict__ A32,
                                                  const float* __restrict__ B32,
                                                  int* __restrict__ idx,
                                                  float* __restrict__ out_idx,
                                                  int K, int CD) {
    #pragma clang fp contract(off)
    extern __shared__ float sm[];
    float* zp = sm;
    float* rm = zp + CD;
    int*   rj = (int*)(rm + 256);
    const int t = blockIdx.x;
    const int tid = threadIdx.x;
    for (int i = tid; i < CD; i += 256) zp[i] = zp32[(size_t)t * CD + i];
    __syncthreads();
    const float A = A32[t];
    float m1 = 3.0e38f; int j1 = 0x7fffffff;
    const int main8 = CD & ~7;
    for (int k = tid; k < K; k += 256) {
        const float* e = emb + (size_t)k * CD;
        float l0 = 0.f, l1 = 0.f, l2 = 0.f, l3 = 0.f;
        for (int m = 0; m < main8; m += 4) {
            l0 += zp[m]     * e[m];
            l1 += zp[m + 1] * e[m + 1];
            l2 += zp[m + 2] * e[m + 2];
            l3 += zp[m + 3] * e[m + 3];
        }
        float M = (l0 + l1) + (l2 + l3);
        for (int i = main8; i < CD; ++i) M += zp[i] * e[i];
        float S = A + B32[k];
        float d = S - 2.f * M;
        if (d < m1) { m1 = d; j1 = k; }
    }
    rm[tid] = m1; rj[tid] = j1;
    __syncthreads();
    if (tid == 0) {
        float gm = 3.0e38f; int gj = 0x7fffffff;
        for (int s = 0; s < 256; ++s) {
            if (rm[s] < gm || (rm[s] == gm && rj[s] < gj)) { gm = rm[s]; gj = rj[s]; }
        }
        idx[t] = gj;
        out_idx[t] = (float)gj;
    }
}

// ---------------- out v2: DOUT=256, CD=64, Wp row in VGPRs, 8 tokens/block ----------
__global__ __launch_bounds__(256) void k_out_v2(const float* __restrict__ emb,
                                                const float* __restrict__ zp32,
                                                const int* __restrict__ idx,
                                                const float* __restrict__ Wp,
                                                const float* __restrict__ bp,
                                                float* __restrict__ out) {
    __shared__ float zq[8 * 64];
    const int tid = threadIdx.x;
    const int tbase = blockIdx.x * 8;
    for (int i = tid; i < 512; i += 256) {
        const int tk = i >> 6, c = i & 63;
        const int t = tbase + tk;
        const float zpv = zp32[(size_t)t * 64 + c];
        zq[i] = zpv + (emb[(size_t)idx[t] * 64 + c] - zpv);
    }
    float4 wp[16];
#pragma unroll
    for (int i = 0; i < 16; ++i) wp[i] = *(const float4*)(Wp + (size_t)tid * 64 + i * 4);
    const float bpd = bp[tid];
    __syncthreads();
#pragma unroll
    for (int tk = 0; tk < 8; ++tk) {
        const float* zr = zq + tk * 64;
        float acc = 0.f;
#pragma unroll
        for (int i = 0; i < 16; ++i) {
            const float4 p = *(const float4*)(zr + i * 4);
            acc += p.x * wp[i].x + p.y * wp[i].y + p.z * wp[i].z + p.w * wp[i].w;
        }
        out[(size_t)(tbase + tk) * 256 + tid] = acc + bpd;
    }
}

// ---------------- out / loss fallbacks ----------------
__global__ __launch_bounds__(256) void k_out(const float* __restrict__ emb,
                                             const float* __restrict__ zp32,
                                             const int* __restrict__ idx,
                                             const float* __restrict__ Wp,
                                             const float* __restrict__ bp,
                                             float* __restrict__ out,
                                             int DOUT, int CD) {
    extern __shared__ float zq[];
    const int t = blockIdx.x;
    const int tid = threadIdx.x;
    const int k = idx[t];
    for (int i = tid; i < CD; i += 256) {
        const float zpv = zp32[(size_t)t * CD + i];
        zq[i] = zpv + (emb[(size_t)k * CD + i] - zpv);
    }
    __syncthreads();
    for (int d = tid; d < DOUT; d += 256) {
        const float* w = Wp + (size_t)d * CD;
        float acc = 0.f;
        for (int c = 0; c < CD; ++c) acc += zq[c] * w[c];
        out[(size_t)t * DOUT + d] = acc + bp[d];
    }
}

__global__ __launch_bounds__(256) void k_loss1(const float* __restrict__ zp32,
                                               const float* __restrict__ emb,
                                               const int* __restrict__ idx,
                                               double* __restrict__ part,
                                               long long total, int CD) {
    double acc = 0.0;
    const long long stride = (long long)gridDim.x * 256;
    for (long long e = (long long)blockIdx.x * 256 + threadIdx.x; e < total; e += stride) {
        const long long t = e / CD;
        const int c = (int)(e - t * CD);
        const float df = emb[(size_t)idx[t] * CD + c] - zp32[e];
        acc += (double)df * (double)df;
    }
    __shared__ double red[256];
    red[threadIdx.x] = acc;
    __syncthreads();
    for (int s = 128; s > 0; s >>= 1) {
        if (threadIdx.x < s) red[threadIdx.x] += red[threadIdx.x + s];
        __syncthreads();
    }
    if (threadIdx.x == 0) part[blockIdx.x] = red[0];
}

__global__ __launch_bounds__(256) void k_loss2(const double* __restrict__ part,
                                               float* __restrict__ out_loss,
                                               double denom, int n) {
    __shared__ double red[256];
    const int tid = threadIdx.x;
    red[tid] = (tid < n) ? part[tid] : 0.0;
    __syncthreads();
    for (int s = 128; s > 0; s >>= 1) {
        if (tid < s) red[tid] += red[tid + s];
        __syncthreads();
    }
    if (tid == 0) *out_loss = (float)(1.25 * red[0] / denom);
}

extern "C" void kernel_launch(void* const* d_in, const int* in_sizes, int n_in,
                              void* d_out, int out_size, void* d_ws, size_t ws_size,
                              hipStream_t stream) {
    const float* z   = (const float*)d_in[0];
    const float* Wq  = (const float*)d_in[1];
    const float* bq  = (const float*)d_in[2];
    const float* emb = (const float*)d_in[3];
    const float* Wp  = (const float*)d_in[4];
    const float* bp  = (const float*)d_in[5];

    const int CD   = in_sizes[2];
    const int DIN  = in_sizes[1] / CD;
    const int DOUT = in_sizes[5];
    const int K    = in_sizes[3] / CD;
    const long long T = (long long)in_sizes[0] / DIN;

    float* out      = (float*)d_out;
    float* out_idx  = out + (size_t)T * DOUT;
    float* out_loss = out_idx + T;

    char* ws = (char*)d_ws;
    size_t off = 0;
    auto carve = [&](size_t bytes) -> char* {
        char* p = ws + off;
        off = (off + bytes + 255) & ~(size_t)255;
        return p;
    };
    float*  zp32  = (float*)carve((size_t)T * CD * 4);
    float*  A32   = (float*)carve((size_t)T * 4);
    float*  B32   = (float*)carve((size_t)K * 4);
    int*    idx   = (int*)carve((size_t)T * 4);
    double* part  = (double*)carve(128 * 8);
    double* ploss = (double*)carve((size_t)T * 8);

    bool mfma_ok = (CD == 64) && (K % 1024 == 0) && (T % 512 == 0);
    short8v* zpf = nullptr; short8v* ef = nullptr; short8v* bfr = nullptr;
    float* pmax = nullptr; float* thv = nullptr; int* cnt = nullptr; int* cand = nullptr;
    int ztiles = 0, ctiles = 0;
    if (mfma_ok) {
        ztiles = (int)(T / 32);
        ctiles = K / 32;
        zpf  = (short8v*)carve((size_t)ztiles * 256 * 16);
        ef   = (short8v*)carve((size_t)ctiles * 256 * 16);
        bfr  = (short8v*)carve((size_t)ctiles * 64 * 16);
        pmax = (float*)carve((size_t)T * 64 * 4);
        thv  = (float*)carve((size_t)T * 4);
        cnt  = (int*)carve((size_t)T * 4);
        cand = (int*)carve((size_t)T * 16 * 4);
        if (off > ws_size) mfma_ok = false;
    }

    if (CD == 64 && DIN == 256 && T % 32 == 0) {
        k_zp_v3<<<dim3((unsigned)(T / 32)), dim3(512), 0, stream>>>(z, Wq, bq, zp32);
    } else {
        k_zp_np<<<dim3((unsigned)T), dim3(64), (size_t)DIN * 4, stream>>>(z, Wq, bq, zp32, DIN, CD);
    }

    if (CD == 64) {
        k_rowsum2_np<<<dim3((unsigned)((T + 255) / 256)), dim3(256), 0, stream>>>(zp32, A32, (int)T);
        k_rowsum2_np<<<dim3((K + 255) / 256), dim3(256), 0, stream>>>(emb, B32, K);
    } else {
        k_rowsum2_gen<<<dim3((unsigned)((T + 255) / 256)), dim3(256), 0, stream>>>(zp32, A32, (int)T, CD);
        k_rowsum2_gen<<<dim3((K + 255) / 256), dim3(256), 0, stream>>>(emb, B32, K, CD);
    }

    if (mfma_ok) {
        const int zg = ztiles * 256, cg = ctiles * 256, bg = ctiles * 64;
        k_prep_frag<<<dim3((zg + 255) / 256), dim3(256), 0, stream>>>(zp32, zpf, zg, (int)T);
        k_prep_frag<<<dim3((cg + 255) / 256), dim3(256), 0, stream>>>(emb, ef, cg, K);
        k_prep_bfrag<<<dim3((bg + 255) / 256), dim3(256), 0, stream>>>(B32, bfr, bg, K);

        dim3 grid((unsigned)(T / 512), 32);
        k_scan_max<<<grid, dim3(256), 0, stream>>>(zpf, ef, bfr, pmax, (int)T, K);
        k_thresh<<<dim3((unsigned)((T + 255) / 256)), dim3(256), 0, stream>>>(pmax, thv, cnt, (int)T);
        k_scan_collect<<<grid, dim3(256), 0, stream>>>(zpf, ef, bfr, thv, cnt, cand, (int)T, K);
        k_refine_v2<<<dim3((unsigned)((T + 255) / 256)), dim3(256), 0, stream>>>(
            emb, zp32, A32, B32, cnt, cand, (int)T, idx, out_idx, ploss);
        k_loss_red<<<dim3(1), dim3(256), 0, stream>>>(ploss, out_loss, (int)T, (double)T * CD);
    } else {
        const size_t sm = (size_t)CD * 4 + 256 * 4 + 256 * 4;
        k_scan_gen<<<dim3((unsigned)T), dim3(256), sm, stream>>>(
            emb, zp32, A32, B32, idx, out_idx, K, CD);
        k_loss1<<<dim3(128), dim3(256), 0, stream>>>(zp32, emb, idx, part, (long long)T * CD, CD);
        k_loss2<<<dim3(1), dim3(256), 0, stream>>>(part, out_loss, (double)T * CD, 128);
    }

    if (DOUT == 256 && CD == 64 && T % 8 == 0) {
        k_out_v2<<<dim3((unsigned)(T / 8)), dim3(256), 0, stream>>>(emb, zp32, idx, Wp, bp, out);
    } else {
        k_out<<<dim3((unsigned)T), dim3(256), (size_t)CD * 4, stream>>>(emb, zp32, idx, Wp, bp, out, DOUT, CD);
    }
}

// Round 12
// 207.864 us; speedup vs baseline: 3.6065x; 1.0198x over previous
//
#include <hip/hip_runtime.h>
#include <hip/hip_bf16.h>

// ===================================================================================
// Verified (R6-R11, absmax 3.05e-5): argmin bit-replicates numpy-f32:
//   zp  = einsum SSE mod-4 accumulators, reduce (l0+l1)+(l2+l3), + bq
//   A,B = pairwise f32 row-sum-of-squares (AVX512 npyv tree for n=64)
//   d   = fl32( fl32(A + B_k) - fl32(2*M_k) ), first-index ties
// Two-pass MFMA scan (R11, verified): pass-1 max of v=M-B/2; thv = vmax - 1e-5;
// pass-2 bit-identical re-run collects all v >= thv (winner provably present).
// R12: scan blocks LDS-stage their 8-ctile slice (40KB = 4 blocks/CU, 16 waves/CU,
// ef traffic /4); grid.y=64; prep fused: k_prep_tok = zp+A+zpf, k_prep_code = B+ef+bfr.
// ===================================================================================

#define VWIN 1.0e-5f

typedef short short8v __attribute__((ext_vector_type(8)));
typedef float floatx16 __attribute__((ext_vector_type(16)));

__device__ __forceinline__ short f2bf(float x) {           // RTNE f32->bf16
    unsigned u = __builtin_bit_cast(unsigned, x);
    unsigned r = (u + 0x7fffu + ((u >> 16) & 1u)) >> 16;
    return (short)r;
}

__device__ __forceinline__ float np_pairwise64_sq(const float* __restrict__ p) {
    #pragma clang fp contract(off)
    float v[16];
#pragma unroll
    for (int j = 0; j < 16; ++j) {
        float x0 = p[j]      * p[j];
        float x1 = p[j + 32] * p[j + 32];
        float x2 = p[j + 16] * p[j + 16];
        float x3 = p[j + 48] * p[j + 48];
        float r0 = x0 + x1;
        float r1 = x2 + x3;
        v[j] = r0 + r1;
    }
    float s[8], t[4];
#pragma unroll
    for (int j = 0; j < 8; ++j) s[j] = v[j] + v[j + 8];
#pragma unroll
    for (int j = 0; j < 4; ++j) t[j] = s[j] + s[j + 4];
    return (t[0] + t[2]) + (t[1] + t[3]);
}

// ---------------- fused token prep: zp (np-exact) + A + zpf fragments --------------
// CD=64, DIN=256, 32 tokens/block, 512 threads.
__global__ __launch_bounds__(512) void k_prep_tok(const float* __restrict__ z,
                                                  const float* __restrict__ Wq,
                                                  const float* __restrict__ bq,
                                                  float* __restrict__ zp32,
                                                  float* __restrict__ A32,
                                                  short8v* __restrict__ zpf) {
    __shared__ float wq[64 * 129];
    __shared__ float zl[32 * 128];
    __shared__ float zps[32 * 65];
    const int tid  = threadIdx.x;
    const int w    = tid >> 6;
    const int lane = tid & 63;
    const int tbase = blockIdx.x * 32;

    float l[4][4];
#pragma unroll
    for (int i = 0; i < 4; ++i)
#pragma unroll
        for (int j = 0; j < 4; ++j) l[i][j] = 0.f;

    for (int h = 0; h < 2; ++h) {
        __syncthreads();
        for (int i = tid; i < 64 * 128; i += 512) {
            const int c = i >> 7, m = i & 127;
            wq[c * 129 + m] = Wq[(size_t)c * 256 + h * 128 + m];
        }
        for (int i = tid; i < 32 * 128; i += 512) {
            const int t = i >> 7, m = i & 127;
            zl[t * 128 + m] = z[(size_t)(tbase + t) * 256 + h * 128 + m];
        }
        __syncthreads();
        {
            #pragma clang fp contract(off)
            const float* wr  = wq + lane * 129;
            const float* zt0 = zl + (w * 4 + 0) * 128;
            const float* zt1 = zl + (w * 4 + 1) * 128;
            const float* zt2 = zl + (w * 4 + 2) * 128;
            const float* zt3 = zl + (w * 4 + 3) * 128;
            for (int m = 0; m < 128; m += 4) {
                const float w0 = wr[m], w1 = wr[m + 1], w2 = wr[m + 2], w3 = wr[m + 3];
                const float4 p0 = *(const float4*)(zt0 + m);
                const float4 p1 = *(const float4*)(zt1 + m);
                const float4 p2 = *(const float4*)(zt2 + m);
                const float4 p3 = *(const float4*)(zt3 + m);
                l[0][0] += p0.x * w0; l[0][1] += p0.y * w1; l[0][2] += p0.z * w2; l[0][3] += p0.w * w3;
                l[1][0] += p1.x * w0; l[1][1] += p1.y * w1; l[1][2] += p1.z * w2; l[1][3] += p1.w * w3;
                l[2][0] += p2.x * w0; l[2][1] += p2.y * w1; l[2][2] += p2.z * w2; l[2][3] += p2.w * w3;
                l[3][0] += p3.x * w0; l[3][1] += p3.y * w1; l[3][2] += p3.z * w2; l[3][3] += p3.w * w3;
            }
        }
    }
    {
        #pragma clang fp contract(off)
        const float bqc = bq[lane];
#pragma unroll
        for (int tk = 0; tk < 4; ++tk) {
            const float acc = (l[tk][0] + l[tk][1]) + (l[tk][2] + l[tk][3]);
            const float zpv = acc + bqc;
            zp32[(size_t)(tbase + w * 4 + tk) * 64 + lane] = zpv;
            zps[(w * 4 + tk) * 65 + lane] = zpv;
        }
    }
    __syncthreads();
    if (tid < 32) A32[tbase + tid] = np_pairwise64_sq(zps + tid * 65);
    if (tid < 256) {
        const int fl = tid & 63;
        const int s  = tid >> 6;
        const int row = fl & 31;
        const int k0 = s * 16 + (fl >> 5) * 8;
        short8v hv;
        const float* p = zps + row * 65 + k0;
#pragma unroll
        for (int j = 0; j < 8; ++j) hv[j] = f2bf(p[j]);
        zpf[(size_t)(blockIdx.x * 4 + s) * 64 + fl] = hv;
    }
}

// ---------------- fused code prep: B + ef fragments + bfr ----------------
// CD=64, 32 codes/block (one tile), 256 threads.
__global__ __launch_bounds__(256) void k_prep_code(const float* __restrict__ emb,
                                                   float* __restrict__ B32,
                                                   short8v* __restrict__ ef,
                                                   short8v* __restrict__ bfr) {
    __shared__ float et[32 * 65];
    __shared__ float sB[32];
    const int tid = threadIdx.x;
    const int tile = blockIdx.x;
    for (int i = tid; i < 2048; i += 256)
        et[(i >> 6) * 65 + (i & 63)] = emb[(size_t)tile * 2048 + i];
    __syncthreads();
    if (tid < 32) {
        const float b = np_pairwise64_sq(et + tid * 65);
        B32[tile * 32 + tid] = b;
        sB[tid] = b;
    }
    __syncthreads();
    {
        const int fl = tid & 63;
        const int s  = tid >> 6;
        const int row = fl & 31;
        const int k0 = s * 16 + (fl >> 5) * 8;
        short8v hv;
        const float* p = et + row * 65 + k0;
#pragma unroll
        for (int j = 0; j < 8; ++j) hv[j] = f2bf(p[j]);
        ef[(size_t)(tile * 4 + s) * 64 + fl] = hv;
    }
    if (tid < 64) {
        short8v v;
#pragma unroll
        for (int j = 0; j < 8; ++j) v[j] = 0;
        if (tid < 32) v[0] = f2bf(-0.5f * sB[tid]);
        bfr[(size_t)tile * 64 + tid] = v;
    }
}

// ---------------- pass-1: per-token MAX of v = M - B/2, LDS-staged e-slice ----------
// grid (T/512, 64); block stages its 8-ctile slice (40KB LDS) once.
__global__ __launch_bounds__(256) void k_scan_max(const short8v* __restrict__ zpf,
                                                  const short8v* __restrict__ ef,
                                                  const short8v* __restrict__ bfr,
                                                  float* __restrict__ pmax,
                                                  int tokens, int K) {
    __shared__ short8v s_ef[2048];     // 8 ctiles x 4 steps x 64 lanes (32 KB)
    __shared__ short8v s_bf[512];      // 8 ctiles x 64 lanes (8 KB)
    const int tid  = threadIdx.x;
    const int w    = tid >> 6;
    const int lane = tid & 63;
    const int half = lane >> 5;
    const int col  = lane & 31;
    const int ttb  = (blockIdx.x * 4 + w) * 4;
    const int etiles = K / 2048;                  // 8 for K=16384
    const int ct0 = blockIdx.y * etiles;

    for (int i = tid; i < 2048; i += 256) s_ef[i] = ef[(size_t)ct0 * 256 + i];
    for (int i = tid; i < 512;  i += 256) s_bf[i] = bfr[(size_t)ct0 * 64 + i];

    short8v zh[4][4];
#pragma unroll
    for (int q = 0; q < 4; ++q)
#pragma unroll
        for (int s = 0; s < 4; ++s) zh[q][s] = zpf[(size_t)((ttb + q) * 4 + s) * 64 + lane];

    short8v ones;
#pragma unroll
    for (int j = 0; j < 8; ++j) ones[j] = (short)0x3F80;

    __syncthreads();

    float m[4] = {-3.0e38f, -3.0e38f, -3.0e38f, -3.0e38f};

    for (int it = 0; it < etiles; ++it) {
        const short8v bfrag = s_bf[it * 64 + lane];
        short8v eh[4];
#pragma unroll
        for (int s = 0; s < 4; ++s) eh[s] = s_ef[it * 256 + s * 64 + lane];
#pragma unroll
        for (int q = 0; q < 4; ++q) {
            floatx16 acc;
            {
                floatx16 z0;
#pragma unroll
                for (int i = 0; i < 16; ++i) z0[i] = 0.f;
                acc = __builtin_amdgcn_mfma_f32_32x32x16_bf16(bfrag, ones, z0, 0, 0, 0);
            }
#pragma unroll
            for (int s = 0; s < 4; ++s)
                acc = __builtin_amdgcn_mfma_f32_32x32x16_bf16(eh[s], zh[q][s], acc, 0, 0, 0);
            float t0 = fmaxf(acc[0], acc[1]),  t1 = fmaxf(acc[2], acc[3]);
            float t2 = fmaxf(acc[4], acc[5]),  t3 = fmaxf(acc[6], acc[7]);
            float t4 = fmaxf(acc[8], acc[9]),  t5 = fmaxf(acc[10], acc[11]);
            float t6 = fmaxf(acc[12], acc[13]), t7 = fmaxf(acc[14], acc[15]);
            t0 = fmaxf(t0, t1); t2 = fmaxf(t2, t3); t4 = fmaxf(t4, t5); t6 = fmaxf(t6, t7);
            m[q] = fmaxf(m[q], fmaxf(fmaxf(t0, t2), fmaxf(t4, t6)));
        }
    }

#pragma unroll
    for (int q = 0; q < 4; ++q) {
        const int tok = (ttb + q) * 32 + col;
        if (tok < tokens)
            pmax[(size_t)(blockIdx.y * 2 + half) * tokens + tok] = m[q];
    }
}

// ---------------- threshold reduce + counter zero ----------------
__global__ __launch_bounds__(256) void k_thresh(const float* __restrict__ pmax,
                                                float* __restrict__ thv,
                                                int* __restrict__ cnt,
                                                int tokens, int nslots) {
    const int t = blockIdx.x * 256 + threadIdx.x;
    if (t >= tokens) return;
    float m = -3.0e38f;
    for (int s = 0; s < nslots; ++s) m = fmaxf(m, pmax[(size_t)s * tokens + t]);
    thv[t] = m - VWIN;
    cnt[t] = 0;
}

// ---------------- pass-2: collect all codes with v >= thv (bit-identical MFMA) ------
__global__ __launch_bounds__(256) void k_scan_collect(const short8v* __restrict__ zpf,
                                                      const short8v* __restrict__ ef,
                                                      const short8v* __restrict__ bfr,
                                                      const float* __restrict__ thv,
                                                      int* __restrict__ cnt,
                                                      int* __restrict__ cand,
                                                      int tokens, int K) {
    __shared__ short8v s_ef[2048];
    __shared__ short8v s_bf[512];
    const int tid  = threadIdx.x;
    const int w    = tid >> 6;
    const int lane = tid & 63;
    const int half = lane >> 5;
    const int col  = lane & 31;
    const int ttb  = (blockIdx.x * 4 + w) * 4;
    const int etiles = K / 2048;
    const int ct0 = blockIdx.y * etiles;

    for (int i = tid; i < 2048; i += 256) s_ef[i] = ef[(size_t)ct0 * 256 + i];
    for (int i = tid; i < 512;  i += 256) s_bf[i] = bfr[(size_t)ct0 * 64 + i];

    short8v zh[4][4];
#pragma unroll
    for (int q = 0; q < 4; ++q)
#pragma unroll
        for (int s = 0; s < 4; ++s) zh[q][s] = zpf[(size_t)((ttb + q) * 4 + s) * 64 + lane];

    float tv[4];
    int tokq[4];
#pragma unroll
    for (int q = 0; q < 4; ++q) {
        tokq[q] = (ttb + q) * 32 + col;
        tv[q] = (tokq[q] < tokens) ? thv[tokq[q]] : 3.0e38f;
    }

    short8v ones;
#pragma unroll
    for (int j = 0; j < 8; ++j) ones[j] = (short)0x3F80;

    __syncthreads();

    for (int it = 0; it < etiles; ++it) {
        const int ct = ct0 + it;
        const short8v bfrag = s_bf[it * 64 + lane];
        short8v eh[4];
#pragma unroll
        for (int s = 0; s < 4; ++s) eh[s] = s_ef[it * 256 + s * 64 + lane];
#pragma unroll
        for (int q = 0; q < 4; ++q) {
            floatx16 acc;
            {
                floatx16 z0;
#pragma unroll
                for (int i = 0; i < 16; ++i) z0[i] = 0.f;
                acc = __builtin_amdgcn_mfma_f32_32x32x16_bf16(bfrag, ones, z0, 0, 0, 0);
            }
#pragma unroll
            for (int s = 0; s < 4; ++s)
                acc = __builtin_amdgcn_mfma_f32_32x32x16_bf16(eh[s], zh[q][s], acc, 0, 0, 0);
            float t0 = fmaxf(acc[0], acc[1]),  t1 = fmaxf(acc[2], acc[3]);
            float t2 = fmaxf(acc[4], acc[5]),  t3 = fmaxf(acc[6], acc[7]);
            float t4 = fmaxf(acc[8], acc[9]),  t5 = fmaxf(acc[10], acc[11]);
            float t6 = fmaxf(acc[12], acc[13]), t7 = fmaxf(acc[14], acc[15]);
            t0 = fmaxf(t0, t1); t2 = fmaxf(t2, t3); t4 = fmaxf(t4, t5); t6 = fmaxf(t6, t7);
            const float tm = fmaxf(fmaxf(t0, t2), fmaxf(t4, t6));
            if (__any(tm >= tv[q])) {
#pragma unroll
                for (int r = 0; r < 16; ++r) {
                    if (acc[r] >= tv[q]) {
                        const int code = ct * 32 + ((r & 3) + 8 * (r >> 2) + 4 * half);
                        const int p = atomicAdd(&cnt[tokq[q]], 1);
                        if (p < 16) cand[(size_t)tokq[q] * 16 + p] = code;
                    }
                }
            }
        }
    }
}

// ---------------- phase-2: np-exact refine over sorted candidates + fused loss ------
__global__ __launch_bounds__(256) void k_refine_v2(const float* __restrict__ emb,
                                                   const float* __restrict__ zp32,
                                                   const float* __restrict__ A32,
                                                   const float* __restrict__ B32,
                                                   const int* __restrict__ cnt,
                                                   const int* __restrict__ cand,
                                                   int tokens,
                                                   int* __restrict__ idx,
                                                   float* __restrict__ out_idx,
                                                   double* __restrict__ ploss) {
    #pragma clang fp contract(off)
    const int t = blockIdx.x * 256 + threadIdx.x;
    if (t >= tokens) return;

    int n = cnt[t];
    if (n > 16) n = 16;
    int cj[16];
    for (int i = 0; i < n; ++i) {
        const int j = cand[(size_t)t * 16 + i];
        int p = i;
        while (p > 0 && cj[p - 1] > j) { cj[p] = cj[p - 1]; --p; }
        cj[p] = j;
    }

    const float A = A32[t];
    const float* zp = zp32 + (size_t)t * 64;
    float best = 3.0e38f;
    int bj = 0x7fffffff;
    for (int c = 0; c < n; ++c) {
        const int j = cj[c];
        const float* e = emb + (size_t)j * 64;
        float l0 = 0.f, l1 = 0.f, l2 = 0.f, l3 = 0.f;
        for (int m = 0; m < 64; m += 4) {
            l0 += zp[m]     * e[m];
            l1 += zp[m + 1] * e[m + 1];
            l2 += zp[m + 2] * e[m + 2];
            l3 += zp[m + 3] * e[m + 3];
        }
        const float M = (l0 + l1) + (l2 + l3);
        const float S = A + B32[j];
        const float d = S - 2.f * M;
        if (d < best) { best = d; bj = j; }   // ascending j + strict < = first index
    }
    idx[t] = bj;
    out_idx[t] = (float)bj;

    double ls = 0.0;
    const float* e = emb + (size_t)bj * 64;
    for (int m = 0; m < 64; ++m) {
        const float df = e[m] - zp[m];
        ls += (double)df * (double)df;
    }
    ploss[t] = ls;
}

__global__ __launch_bounds__(256) void k_loss_red(const double* __restrict__ ploss,
                                                  float* __restrict__ out_loss,
                                                  int tokens, double denom) {
    __shared__ double red[256];
    double a = 0.0;
    for (int i = threadIdx.x; i < tokens; i += 256) a += ploss[i];
    red[threadIdx.x] = a;
    __syncthreads();
    for (int s = 128; s > 0; s >>= 1) {
        if (threadIdx.x < s) red[threadIdx.x] += red[threadIdx.x + s];
        __syncthreads();
    }
    if (threadIdx.x == 0) *out_loss = (float)(1.25 * red[0] / denom);
}

// ---------------- out v2: DOUT=256, CD=64, Wp row in VGPRs, 8 tokens/block ----------
__global__ __launch_bounds__(256) void k_out_v2(const float* __restrict__ emb,
                                                const float* __restrict__ zp32,
                                                const int* __restrict__ idx,
                                                const float* __restrict__ Wp,
                                                const float* __restrict__ bp,
                                                float* __restrict__ out) {
    __shared__ float zq[8 * 64];
    const int tid = threadIdx.x;
    const int tbase = blockIdx.x * 8;
    for (int i = tid; i < 512; i += 256) {
        const int tk = i >> 6, c = i & 63;
        const int t = tbase + tk;
        const float zpv = zp32[(size_t)t * 64 + c];
        zq[i] = zpv + (emb[(size_t)idx[t] * 64 + c] - zpv);
    }
    float4 wp[16];
#pragma unroll
    for (int i = 0; i < 16; ++i) wp[i] = *(const float4*)(Wp + (size_t)tid * 64 + i * 4);
    const float bpd = bp[tid];
    __syncthreads();
#pragma unroll
    for (int tk = 0; tk < 8; ++tk) {
        const float* zr = zq + tk * 64;
        float acc = 0.f;
#pragma unroll
        for (int i = 0; i < 16; ++i) {
            const float4 p = *(const float4*)(zr + i * 4);
            acc += p.x * wp[i].x + p.y * wp[i].y + p.z * wp[i].z + p.w * wp[i].w;
        }
        out[(size_t)(tbase + tk) * 256 + tid] = acc + bpd;
    }
}

// =============================== fallback kernels ===================================
__global__ __launch_bounds__(64) void k_zp_np(const float* __restrict__ z,
                                              const float* __restrict__ Wq,
                                              const float* __restrict__ bq,
                                              float* __restrict__ zp32,
                                              int DIN, int CD) {
    #pragma clang fp contract(off)
    extern __shared__ float zl[];
    const int t = blockIdx.x;
    const int tid = threadIdx.x;
    for (int i = tid; i < DIN; i += 64) zl[i] = z[(size_t)t * DIN + i];
    __syncthreads();
    const int main8 = DIN & ~7;
    for (int c = tid; c < CD; c += 64) {
        const float* wr = Wq + (size_t)c * DIN;
        float l0 = 0.f, l1 = 0.f, l2 = 0.f, l3 = 0.f;
        for (int m = 0; m < main8; m += 4) {
            l0 += zl[m]     * wr[m];
            l1 += zl[m + 1] * wr[m + 1];
            l2 += zl[m + 2] * wr[m + 2];
            l3 += zl[m + 3] * wr[m + 3];
        }
        float acc = (l0 + l1) + (l2 + l3);
        for (int i = main8; i < DIN; ++i) acc += zl[i] * wr[i];
        zp32[(size_t)t * CD + c] = acc + bq[c];
    }
}

__global__ __launch_bounds__(256) void k_rowsum2_np(const float* __restrict__ src,
                                                    float* __restrict__ dst,
                                                    int rows) {
    #pragma clang fp contract(off)
    const int r = blockIdx.x * 256 + threadIdx.x;
    if (r >= rows) return;
    dst[r] = np_pairwise64_sq(src + (size_t)r * 64);
}

__global__ __launch_bounds__(256) void k_rowsum2_gen(const float* __restrict__ src,
                                                     float* __restrict__ dst,
                                                     int rows, int CD) {
    #pragma clang fp contract(off)
    const int r = blockIdx.x * 256 + threadIdx.x;
    if (r >= rows) return;
    const float* p = src + (size_t)r * CD;
    if (CD < 8) {
        float a = 0.f;
        for (int i = 0; i < CD; ++i) a += p[i] * p[i];
        dst[r] = a;
        return;
    }
    float acc[8];
#pragma unroll
    for (int j = 0; j < 8; ++j) acc[j] = p[j] * p[j];
    const int main8 = CD & ~7;
    for (int i = 8; i < main8; i += 8)
#pragma unroll
        for (int j = 0; j < 8; ++j) acc[j] += p[i + j] * p[i + j];
    float res = ((acc[0] + acc[1]) + (acc[2] + acc[3])) + ((acc[4] + acc[5]) + (acc[6] + acc[7]));
    for (int i = main8; i < CD; ++i) res += p[i] * p[i];
    dst[r] = res;
}

__global__ __launch_bounds__(256) void k_scan_gen(const float* __restrict__ emb,
                                                  const float* __restrict__ zp32,
                                                  const float* __restrict__ A32,
                                                  const float* __restrict__ B32,
                                                  int* __restrict__ idx,
                                                  float* __restrict__ out_idx,
                                                  int K, int CD) {
    #pragma clang fp contract(off)
    extern __shared__ float sm[];
    float* zp = sm;
    float* rm = zp + CD;
    int*   rj = (int*)(rm + 256);
    const int t = blockIdx.x;
    const int tid = threadIdx.x;
    for (int i = tid; i < CD; i += 256) zp[i] = zp32[(size_t)t * CD + i];
    __syncthreads();
    const float A = A32[t];
    float m1 = 3.0e38f; int j1 = 0x7fffffff;
    const int main8 = CD & ~7;
    for (int k = tid; k < K; k += 256) {
        const float* e = emb + (size_t)k * CD;
        float l0 = 0.f, l1 = 0.f, l2 = 0.f, l3 = 0.f;
        for (int m = 0; m < main8; m += 4) {
            l0 += zp[m]     * e[m];
            l1 += zp[m + 1] * e[m + 1];
            l2 += zp[m + 2] * e[m + 2];
            l3 += zp[m + 3] * e[m + 3];
        }
        float M = (l0 + l1) + (l2 + l3);
        for (int i = main8; i < CD; ++i) M += zp[i] * e[i];
        float S = A + B32[k];
        float d = S - 2.f * M;
        if (d < m1) { m1 = d; j1 = k; }
    }
    rm[tid] = m1; rj[tid] = j1;
    __syncthreads();
    if (tid == 0) {
        float gm = 3.0e38f; int gj = 0x7fffffff;
        for (int s = 0; s < 256; ++s) {
            if (rm[s] < gm || (rm[s] == gm && rj[s] < gj)) { gm = rm[s]; gj = rj[s]; }
        }
        idx[t] = gj;
        out_idx[t] = (float)gj;
    }
}

__global__ __launch_bounds__(256) void k_out(const float* __restrict__ emb,
                                             const float* __restrict__ zp32,
                                             const int* __restrict__ idx,
                                             const float* __restrict__ Wp,
                                             const float* __restrict__ bp,
                                             float* __restrict__ out,
                                             int DOUT, int CD) {
    extern __shared__ float zq[];
    const int t = blockIdx.x;
    const int tid = threadIdx.x;
    const int k = idx[t];
    for (int i = tid; i < CD; i += 256) {
        const float zpv = zp32[(size_t)t * CD + i];
        zq[i] = zpv + (emb[(size_t)k * CD + i] - zpv);
    }
    __syncthreads();
    for (int d = tid; d < DOUT; d += 256) {
        const float* w = Wp + (size_t)d * CD;
        float acc = 0.f;
        for (int c = 0; c < CD; ++c) acc += zq[c] * w[c];
        out[(size_t)t * DOUT + d] = acc + bp[d];
    }
}

__global__ __launch_bounds__(256) void k_loss1(const float* __restrict__ zp32,
                                               const float* __restrict__ emb,
                                               const int* __restrict__ idx,
                                               double* __restrict__ part,
                                               long long total, int CD) {
    double acc = 0.0;
    const long long stride = (long long)gridDim.x * 256;
    for (long long e = (long long)blockIdx.x * 256 + threadIdx.x; e < total; e += stride) {
        const long long t = e / CD;
        const int c = (int)(e - t * CD);
        const float df = emb[(size_t)idx[t] * CD + c] - zp32[e];
        acc += (double)df * (double)df;
    }
    __shared__ double red[256];
    red[threadIdx.x] = acc;
    __syncthreads();
    for (int s = 128; s > 0; s >>= 1) {
        if (threadIdx.x < s) red[threadIdx.x] += red[threadIdx.x + s];
        __syncthreads();
    }
    if (threadIdx.x == 0) part[blockIdx.x] = red[0];
}

__global__ __launch_bounds__(256) void k_loss2(const double* __restrict__ part,
                                               float* __restrict__ out_loss,
                                               double denom, int n) {
    __shared__ double red[256];
    const int tid = threadIdx.x;
    red[tid] = (tid < n) ? part[tid] : 0.0;
    __syncthreads();
    for (int s = 128; s > 0; s >>= 1) {
        if (tid < s) red[tid] += red[tid + s];
        __syncthreads();
    }
    if (tid == 0) *out_loss = (float)(1.25 * red[0] / denom);
}

extern "C" void kernel_launch(void* const* d_in, const int* in_sizes, int n_in,
                              void* d_out, int out_size, void* d_ws, size_t ws_size,
                              hipStream_t stream) {
    const float* z   = (const float*)d_in[0];
    const float* Wq  = (const float*)d_in[1];
    const float* bq  = (const float*)d_in[2];
    const float* emb = (const float*)d_in[3];
    const float* Wp  = (const float*)d_in[4];
    const float* bp  = (const float*)d_in[5];

    const int CD   = in_sizes[2];
    const int DIN  = in_sizes[1] / CD;
    const int DOUT = in_sizes[5];
    const int K    = in_sizes[3] / CD;
    const long long T = (long long)in_sizes[0] / DIN;

    float* out      = (float*)d_out;
    float* out_idx  = out + (size_t)T * DOUT;
    float* out_loss = out_idx + T;

    char* ws = (char*)d_ws;
    size_t off = 0;
    auto carve = [&](size_t bytes) -> char* {
        char* p = ws + off;
        off = (off + bytes + 255) & ~(size_t)255;
        return p;
    };
    float*  zp32  = (float*)carve((size_t)T * CD * 4);
    float*  A32   = (float*)carve((size_t)T * 4);
    float*  B32   = (float*)carve((size_t)K * 4);
    int*    idx   = (int*)carve((size_t)T * 4);
    double* part  = (double*)carve(128 * 8);
    double* ploss = (double*)carve((size_t)T * 8);

    bool mfma_ok = (CD == 64) && (K % 2048 == 0) && (T % 512 == 0);
    short8v* zpf = nullptr; short8v* ef = nullptr; short8v* bfr = nullptr;
    float* pmax = nullptr; float* thv = nullptr; int* cnt = nullptr; int* cand = nullptr;
    const int NSLICE = 64;
    if (mfma_ok) {
        const int ztiles = (int)(T / 32);
        const int ctiles = K / 32;
        zpf  = (short8v*)carve((size_t)ztiles * 256 * 16);
        ef   = (short8v*)carve((size_t)ctiles * 256 * 16);
        bfr  = (short8v*)carve((size_t)ctiles * 64 * 16);
        pmax = (float*)carve((size_t)T * NSLICE * 2 * 4);
        thv  = (float*)carve((size_t)T * 4);
        cnt  = (int*)carve((size_t)T * 4);
        cand = (int*)carve((size_t)T * 16 * 4);
        if (off > ws_size) mfma_ok = false;
    }

    const bool fused_tok = mfma_ok && (DIN == 256);

    if (fused_tok) {
        k_prep_tok<<<dim3((unsigned)(T / 32)), dim3(512), 0, stream>>>(z, Wq, bq, zp32, A32, zpf);
    } else {
        k_zp_np<<<dim3((unsigned)T), dim3(64), (size_t)DIN * 4, stream>>>(z, Wq, bq, zp32, DIN, CD);
        if (CD == 64)
            k_rowsum2_np<<<dim3((unsigned)((T + 255) / 256)), dim3(256), 0, stream>>>(zp32, A32, (int)T);
        else
            k_rowsum2_gen<<<dim3((unsigned)((T + 255) / 256)), dim3(256), 0, stream>>>(zp32, A32, (int)T, CD);
    }

    if (mfma_ok) {
        if (!fused_tok) {
            // zpf from zp32 via a small inline prep using k_prep_code-style is not
            // available; reuse generic fragment path: emulate with prep_code? No —
            // fall back to scan_gen in this (unencountered) configuration.
        }
        k_prep_code<<<dim3(K / 32), dim3(256), 0, stream>>>(emb, B32, ef, bfr);
    } else if (CD == 64) {
        k_rowsum2_np<<<dim3((K + 255) / 256), dim3(256), 0, stream>>>(emb, B32, K);
    } else {
        k_rowsum2_gen<<<dim3((K + 255) / 256), dim3(256), 0, stream>>>(emb, B32, K, CD);
    }

    if (mfma_ok && fused_tok) {
        dim3 grid((unsigned)(T / 512), NSLICE);
        k_scan_max<<<grid, dim3(256), 0, stream>>>(zpf, ef, bfr, pmax, (int)T, K);
        k_thresh<<<dim3((unsigned)((T + 255) / 256)), dim3(256), 0, stream>>>(
            pmax, thv, cnt, (int)T, NSLICE * 2);
        k_scan_collect<<<grid, dim3(256), 0, stream>>>(zpf, ef, bfr, thv, cnt, cand, (int)T, K);
        k_refine_v2<<<dim3((unsigned)((T + 255) / 256)), dim3(256), 0, stream>>>(
            emb, zp32, A32, B32, cnt, cand, (int)T, idx, out_idx, ploss);
        k_loss_red<<<dim3(1), dim3(256), 0, stream>>>(ploss, out_loss, (int)T, (double)T * CD);
    } else {
        const size_t sm = (size_t)CD * 4 + 256 * 4 + 256 * 4;
        k_scan_gen<<<dim3((unsigned)T), dim3(256), sm, stream>>>(
            emb, zp32, A32, B32, idx, out_idx, K, CD);
        k_loss1<<<dim3(128), dim3(256), 0, stream>>>(zp32, emb, idx, part, (long long)T * CD, CD);
        k_loss2<<<dim3(1), dim3(256), 0, stream>>>(part, out_loss, (double)T * CD, 128);
    }

    if (DOUT == 256 && CD == 64 && T % 8 == 0) {
        k_out_v2<<<dim3((unsigned)(T / 8)), dim3(256), 0, stream>>>(emb, zp32, idx, Wp, bp, out);
    } else {
        k_out<<<dim3((unsigned)T), dim3(256), (size_t)CD * 4, stream>>>(emb, zp32, idx, Wp, bp, out, DOUT, CD);
    }
}